// Round 3
// baseline (1220.418 us; speedup 1.0000x reference)
//
#include <hip/hip_runtime.h>
#include <hip/hip_bf16.h>
#include <math.h>

typedef float floatx4 __attribute__((ext_vector_type(4)));
typedef short bf16x8 __attribute__((ext_vector_type(8)));   // 8 bf16 in 4 VGPRs

__device__ __forceinline__ unsigned short f2bf(float x) {
    union { float f; unsigned int u; } v; v.f = x;
    unsigned int r = v.u + 0x7fffu + ((v.u >> 16) & 1u);    // RNE
    return (unsigned short)(r >> 16);
}

__device__ __forceinline__ void load_lds16(const void* g, void* l) {
    __builtin_amdgcn_global_load_lds(
        (const __attribute__((address_space(1))) unsigned int*)(uintptr_t)g,
        (__attribute__((address_space(3))) unsigned int*)(uintptr_t)l, 16, 0, 0);
}

// ---------------- pos embed + input add (float math: |err| ~1e-6 << bf16 noise) ----
__global__ void posembed_kernel(const float* __restrict__ xin, float* __restrict__ xb) {
    int idx = blockIdx.x * 256 + threadIdx.x;     // 2*1024*1024
    int c = idx & 1023;
    int n = (idx >> 10) & 1023;
    int pos = (c < 512) ? (n & 31) : (n >> 5);
    int cc = c & 511;
    int k = cc & 255;
    float om = expf(-(float)k * (9.210340371976184f / 256.0f));
    float arg = (float)pos * om;
    float e = (cc < 256) ? sinf(arg) : cosf(arg);
    xb[idx] = xin[idx] + e;
}

// ---------------- layernorm over C=1024, bf16 output ----------------
__global__ __launch_bounds__(256) void ln_kernel(const float* __restrict__ X,
                                                 unsigned short* __restrict__ Y,
                                                 const float* __restrict__ g,
                                                 const float* __restrict__ b,
                                                 float eps, int affine) {
    int row = blockIdx.x;
    const float4* xr = (const float4*)(X + (size_t)row * 1024);
    float4 x = xr[threadIdx.x];
    float s = x.x + x.y + x.z + x.w;
    float sq = x.x * x.x + x.y * x.y + x.z * x.z + x.w * x.w;
    __shared__ float red[8];
    #pragma unroll
    for (int off = 32; off; off >>= 1) { s += __shfl_xor(s, off); sq += __shfl_xor(sq, off); }
    int wid = threadIdx.x >> 6, lane = threadIdx.x & 63;
    if (!lane) { red[wid] = s; red[wid + 4] = sq; }
    __syncthreads();
    s = red[0] + red[1] + red[2] + red[3];
    sq = red[4] + red[5] + red[6] + red[7];
    float mu = s * (1.f / 1024.f);
    float var = sq * (1.f / 1024.f) - mu * mu;
    float rs = rsqrtf(var + eps);
    int c = threadIdx.x * 4;
    float4 y;
    if (affine) {
        y.x = (x.x - mu) * rs * g[c + 0] + b[c + 0];
        y.y = (x.y - mu) * rs * g[c + 1] + b[c + 1];
        y.z = (x.z - mu) * rs * g[c + 2] + b[c + 2];
        y.w = (x.w - mu) * rs * g[c + 3] + b[c + 3];
    } else {
        y.x = (x.x - mu) * rs; y.y = (x.y - mu) * rs;
        y.z = (x.z - mu) * rs; y.w = (x.w - mu) * rs;
    }
    ushort4 o;
    o.x = f2bf(y.x); o.y = f2bf(y.y); o.z = f2bf(y.z); o.w = f2bf(y.w);
    *(ushort4*)(Y + (size_t)row * 1024 + c) = o;
}

// ---- merged qk-norm + V transpose: one pass over qkv ----
__global__ __launch_bounds__(256) void qkvprep_kernel(const float* __restrict__ qkv,
                                                      const float* __restrict__ nqg,
                                                      const float* __restrict__ nqb,
                                                      const float* __restrict__ nkg,
                                                      const float* __restrict__ nkb,
                                                      unsigned short* __restrict__ Qb,
                                                      unsigned short* __restrict__ Kb,
                                                      unsigned short* __restrict__ Vt) {
    __shared__ float t[64][65];
    int tid = threadIdx.x;
    int l0 = blockIdx.x * 64, h = blockIdx.y, b = blockIdx.z;
    for (int i = tid; i < 4096; i += 256) {
        int lr = i >> 6, dd = i & 63;
        t[lr][dd] = qkv[((size_t)(b * 1024 + l0 + lr)) * 3072 + 2048 + h * 64 + dd];
    }
    __syncthreads();
    for (int i = tid; i < 4096; i += 256) {
        int dd = i >> 6, lc = i & 63;
        Vt[((size_t)((b * 16 + h) * 64 + dd)) * 1024 + l0 + lc] = f2bf(t[lc][dd]);
    }
    int wave = tid >> 6, lane = tid & 63;
    float gq = nqg[lane], bq = nqb[lane], gk = nkg[lane], bk = nkb[lane];
    for (int i = 0; i < 16; i++) {
        int l = l0 + wave + 4 * i;
        const float* base = qkv + (size_t)(b * 1024 + l) * 3072 + h * 64 + lane;
        #pragma unroll
        for (int part = 0; part < 2; part++) {
            float v = base[part * 1024];
            float s = v, sq = v * v;
            #pragma unroll
            for (int off = 32; off; off >>= 1) { s += __shfl_xor(s, off); sq += __shfl_xor(sq, off); }
            float mu = s * (1.f / 64.f);
            float var = sq * (1.f / 64.f) - mu * mu;
            float rs = rsqrtf(var + 1e-5f);
            float y = (v - mu) * rs * (part ? gk : gq) + (part ? bk : bq);
            unsigned short* dst = part ? Kb : Qb;
            dst[(size_t)(b * 1024 + l) * 1024 + h * 64 + lane] = f2bf(y * (part ? 1.f : 0.125f));
        }
    }
}

// ---- MFMA flash attention: block = (64 q-rows, head, b); 4 waves x 16 rows ----
// K/V per (b,h) is 256KB -> L2-resident and reused by 16 q-blocks: read
// fragments DIRECTLY from global (no LDS staging, no barriers). Pl is
// per-wave scratch only -> kernel has zero __syncthreads; waves stream
// independently and 8 waves/CU hide the L2 latency.
__global__ __launch_bounds__(256) void attn_mfma(const unsigned short* __restrict__ Qb,
                                                 const unsigned short* __restrict__ Kb,
                                                 const unsigned short* __restrict__ Vt,
                                                 unsigned short* __restrict__ ob) {
    __shared__ short Pl[4][16 * 72];
    int tid = threadIdx.x;
    int lane = tid & 63, wave = tid >> 6;
    int ln16 = lane & 15, q = lane >> 4;
    int b = blockIdx.z, h = blockIdx.y, q0 = blockIdx.x * 64;

    const unsigned short* qrow = Qb + ((size_t)(b * 1024 + q0 + wave * 16 + ln16)) * 1024 + h * 64;
    bf16x8 qf0 = *(const bf16x8*)(qrow + q * 8);
    bf16x8 qf1 = *(const bf16x8*)(qrow + 32 + q * 8);

    floatx4 o[4];
    #pragma unroll
    for (int td = 0; td < 4; td++) o[td] = (floatx4){0.f, 0.f, 0.f, 0.f};
    float mrow[4] = {-1e30f, -1e30f, -1e30f, -1e30f};
    float lrow[4] = {0.f, 0.f, 0.f, 0.f};

    // per-lane fragment bases: K row = (l0 + t*16 + ln16), 8 bf16 at q*8 / 32+q*8
    const unsigned short* kbase = Kb + ((size_t)(b * 1024 + ln16)) * 1024 + h * 64 + q * 8;
    const unsigned short* vbase = Vt + ((size_t)((b * 16 + h) * 64 + ln16)) * 1024 + q * 8;

    for (int ch = 0; ch < 16; ch++) {
        int l0 = ch * 64;
        // ---- load all K fragments for this chunk up front (ILP) ----
        bf16x8 kf[4][2];
        #pragma unroll
        for (int t = 0; t < 4; t++) {
            const unsigned short* kp = kbase + (size_t)(l0 + t * 16) * 1024;
            kf[t][0] = *(const bf16x8*)kp;
            kf[t][1] = *(const bf16x8*)(kp + 32);
        }
        floatx4 s[4];
        #pragma unroll
        for (int t = 0; t < 4; t++) {
            s[t] = (floatx4){0.f, 0.f, 0.f, 0.f};
            s[t] = __builtin_amdgcn_mfma_f32_16x16x32_bf16(qf0, kf[t][0], s[t], 0, 0, 0);
            s[t] = __builtin_amdgcn_mfma_f32_16x16x32_bf16(qf1, kf[t][1], s[t], 0, 0, 0);
        }
        // ---- prefetch V fragments while softmax runs ----
        bf16x8 vf[4][2];
        #pragma unroll
        for (int td = 0; td < 4; td++) {
            const unsigned short* vp = vbase + (size_t)(td * 16) * 1024 + l0;
            vf[td][0] = *(const bf16x8*)vp;
            vf[td][1] = *(const bf16x8*)(vp + 32);
        }
        float cm[4], rs[4], p[4][4];
        #pragma unroll
        for (int r = 0; r < 4; r++)
            cm[r] = fmaxf(fmaxf(s[0][r], s[1][r]), fmaxf(s[2][r], s[3][r]));
        #pragma unroll
        for (int off = 1; off < 16; off <<= 1) {
            #pragma unroll
            for (int r = 0; r < 4; r++) cm[r] = fmaxf(cm[r], __shfl_xor(cm[r], off));
        }
        #pragma unroll
        for (int r = 0; r < 4; r++) {
            float mnew = fmaxf(mrow[r], cm[r]);
            float alpha = __expf(mrow[r] - mnew);
            mrow[r] = mnew;
            rs[r] = 0.f;
            #pragma unroll
            for (int t = 0; t < 4; t++) {
                p[t][r] = __expf(s[t][r] - mnew);
                rs[r] += p[t][r];
            }
            lrow[r] *= alpha;
            #pragma unroll
            for (int td = 0; td < 4; td++) o[td][r] *= alpha;
        }
        #pragma unroll
        for (int off = 1; off < 16; off <<= 1) {
            #pragma unroll
            for (int r = 0; r < 4; r++) rs[r] += __shfl_xor(rs[r], off);
        }
        #pragma unroll
        for (int r = 0; r < 4; r++) lrow[r] += rs[r];

        // Pl[wave] is written and read by the SAME wave only: no barrier needed.
        short* pw = &Pl[wave][0];
        #pragma unroll
        for (int t = 0; t < 4; t++)
            #pragma unroll
            for (int r = 0; r < 4; r++)
                pw[(q * 4 + r) * 72 + t * 16 + ln16] = (short)f2bf(p[t][r]);
        bf16x8 pf0 = *(const bf16x8*)&pw[ln16 * 72 + q * 8];
        bf16x8 pf1 = *(const bf16x8*)&pw[ln16 * 72 + 32 + q * 8];
        #pragma unroll
        for (int td = 0; td < 4; td++) {
            o[td] = __builtin_amdgcn_mfma_f32_16x16x32_bf16(pf0, vf[td][0], o[td], 0, 0, 0);
            o[td] = __builtin_amdgcn_mfma_f32_16x16x32_bf16(pf1, vf[td][1], o[td], 0, 0, 0);
        }
    }
    #pragma unroll
    for (int td = 0; td < 4; td++) {
        #pragma unroll
        for (int r = 0; r < 4; r++) {
            int row = q0 + wave * 16 + q * 4 + r;
            int col = h * 64 + td * 16 + ln16;
            ob[((size_t)(b * 1024 + row)) * 1024 + col] = f2bf(o[td][r] / lrow[r]);
        }
    }
}

// ------- batched weight transpose + bf16: in fp32 [z][K][N] -> out bf16 [z][N][K] ----
__global__ __launch_bounds__(256) void wtrans_kernel(const float* __restrict__ in,
                                                     unsigned short* __restrict__ out,
                                                     int K, int N) {
    __shared__ float t[64][65];
    int n0 = blockIdx.x * 64, k0 = blockIdx.y * 64, z = blockIdx.z;
    in  += (size_t)z * K * N;
    out += (size_t)z * N * K;
    for (int i = threadIdx.x; i < 4096; i += 256) {
        int kr = i >> 6, nc = i & 63;
        t[kr][nc] = in[(size_t)(k0 + kr) * N + n0 + nc];
    }
    __syncthreads();
    for (int i = threadIdx.x; i < 4096; i += 256) {
        int nr = i >> 6, kc = i & 63;
        out[(size_t)(n0 + nr) * K + k0 + kc] = f2bf(t[kc][nr]);
    }
}

// ------- bf16 MFMA GEMM, BK=64, XOR-swizzled LDS -------------------------------
// C = act(A@B + bias)[+C]; A[M][lda] bf16, Bt[N][lda] bf16.
// SPLITK: blockIdx.z selects K-chunk of size K; raw partials to Cf + z*M*N.
template <int BM, int BN, int WM, int WN, int ACT, bool ADDC, bool OUTBF16, bool SPLITK>
__global__ __launch_bounds__(256) void gemm_bf16(const unsigned short* __restrict__ A,
                                                 const unsigned short* __restrict__ Bt,
                                                 const float* __restrict__ bias,
                                                 float* __restrict__ Cf,
                                                 unsigned short* __restrict__ Cb,
                                                 int M, int N, int K, int lda) {
    constexpr int MT = BM / (WM * 16);
    constexpr int NT = BN / (WN * 16);
    __shared__ short As[BM * 64];
    __shared__ short Bs[BN * 64];
    int tid = threadIdx.x;
    int lane = tid & 63, wave = tid >> 6;
    int wm = wave / WN, wn = wave % WN;
    int ln16 = lane & 15, q = lane >> 4;
    int m0 = blockIdx.y * BM, n0 = blockIdx.x * BN;
    int kOff = SPLITK ? blockIdx.z * K : 0;

    floatx4 acc[MT][NT];
    #pragma unroll
    for (int i = 0; i < MT; i++)
        #pragma unroll
        for (int j = 0; j < NT; j++) acc[i][j] = (floatx4){0.f, 0.f, 0.f, 0.f};

    int kSteps = K >> 6;
    for (int ks = 0; ks < kSteps; ks++) {
        int k0 = kOff + (ks << 6);
        #pragma unroll
        for (int it = 0; it < BM / 32; it++) {
            int i = tid + it * 256;
            int row = i >> 3, gc = (i & 7) ^ (row & 7);   // XOR chunk swizzle
            load_lds16(A + (size_t)(m0 + row) * lda + k0 + gc * 8, &As[i * 8]);
        }
        #pragma unroll
        for (int it = 0; it < BN / 32; it++) {
            int i = tid + it * 256;
            int row = i >> 3, gc = (i & 7) ^ (row & 7);
            load_lds16(Bt + (size_t)(n0 + row) * lda + k0 + gc * 8, &Bs[i * 8]);
        }
        __syncthreads();
        bf16x8 af[2][MT], bf[2][NT];
        #pragma unroll
        for (int h = 0; h < 2; h++) {
            #pragma unroll
            for (int mi = 0; mi < MT; mi++) {
                int row = wm * (BM / WM) + mi * 16 + ln16;
                af[h][mi] = *(const bf16x8*)&As[row * 64 + (((h * 4 + q) ^ (row & 7)) * 8)];
            }
            #pragma unroll
            for (int ni = 0; ni < NT; ni++) {
                int row = wn * (BN / WN) + ni * 16 + ln16;
                bf[h][ni] = *(const bf16x8*)&Bs[row * 64 + (((h * 4 + q) ^ (row & 7)) * 8)];
            }
        }
        #pragma unroll
        for (int h = 0; h < 2; h++)
            #pragma unroll
            for (int mi = 0; mi < MT; mi++)
                #pragma unroll
                for (int ni = 0; ni < NT; ni++)
                    acc[mi][ni] = __builtin_amdgcn_mfma_f32_16x16x32_bf16(af[h][mi], bf[h][ni], acc[mi][ni], 0, 0, 0);
        __syncthreads();
    }

    int q4 = q * 4;
    float* Cp = SPLITK ? (Cf + (size_t)blockIdx.z * M * N) : Cf;
    #pragma unroll
    for (int ni = 0; ni < NT; ni++) {
        int col = n0 + wn * (BN / WN) + ni * 16 + ln16;
        float bv = SPLITK ? 0.f : bias[col];
        #pragma unroll
        for (int mi = 0; mi < MT; mi++) {
            #pragma unroll
            for (int r = 0; r < 4; r++) {
                int row = m0 + wm * (BM / WM) + mi * 16 + q4 + r;
                size_t off = (size_t)row * N + col;
                float v = acc[mi][ni][r] + bv;
                if (!SPLITK && ACT == 1) v = 0.5f * v * (1.f + erff(v * 0.70710678118654752f));
                if (!SPLITK && ADDC) v += Cf[off];
                if (!SPLITK && OUTBF16) Cb[off] = f2bf(v);
                else Cp[off] = v;
            }
        }
    }
}

// ------- split-K reduce: xb += P0 + P1 + bias (fc2 epilogue) -------
__global__ __launch_bounds__(256) void skreduce_kernel(const float* __restrict__ P,
                                                       const float* __restrict__ bias,
                                                       float* __restrict__ xb) {
    int idx = blockIdx.x * 256 + threadIdx.x;          // float4 index, 2048*1024/4
    float4 a = ((const float4*)P)[idx];
    float4 b = ((const float4*)P)[idx + 524288];
    float4 x = ((float4*)xb)[idx];
    const float4 bb = *(const float4*)(bias + (idx & 255) * 4);
    x.x += a.x + b.x + bb.x;
    x.y += a.y + b.y + bb.y;
    x.z += a.z + b.z + bb.z;
    x.w += a.w + b.w + bb.w;
    ((float4*)xb)[idx] = x;
}

// ---------------- unpatchify ----------------
__global__ void unpatchify_kernel(const float* __restrict__ xf, float* __restrict__ img) {
    int idx = blockIdx.x * 256 + threadIdx.x;
    int x = idx & 63, y = (idx >> 6) & 63, ch = (idx >> 12) & 63, b = idx >> 18;
    int hh = y >> 1, ww = x >> 1, p = y & 1, qq = x & 1;
    img[idx] = xf[((size_t)b * 1024 + hh * 32 + ww) * 256 + ch * 4 + p * 2 + qq];
}

// ------- conv1: 64->16, 3x3, pad1, relu -------
__global__ __launch_bounds__(256) void conv1_kernel(const float* __restrict__ img,
                                                    const float* __restrict__ w,
                                                    const float* __restrict__ bias,
                                                    float* __restrict__ out) {
    __shared__ float Ls[64 * 3 * 66];
    __shared__ float Ws[16 * 580];
    int tid = threadIdx.x;
    int y = blockIdx.x, b = blockIdx.y;
    for (int i = tid; i < 9216; i += 256) {
        int oc = i / 576, rem = i % 576;
        Ws[oc * 580 + rem] = w[i];
    }
    for (int i = tid; i < 12288; i += 256) {
        int r = i >> 6, x = i & 63;
        int ic = r / 3, ky = r % 3;
        int yy = y + ky - 1;
        float v = (yy >= 0 && yy < 64) ? img[((size_t)(b * 64 + ic) * 64 + yy) * 64 + x] : 0.f;
        Ls[(ic * 3 + ky) * 66 + x + 1] = v;
        if (x == 0)  Ls[(ic * 3 + ky) * 66 + 0]  = 0.f;
        if (x == 63) Ls[(ic * 3 + ky) * 66 + 65] = 0.f;
    }
    __syncthreads();
    int oc = tid >> 4, xg = (tid & 15) * 4;
    float bv = bias[oc];
    float acc0 = bv, acc1 = bv, acc2 = bv, acc3 = bv;
    for (int ic = 0; ic < 64; ic++) {
        const float* wr = &Ws[oc * 580 + ic * 9];
        float w00 = wr[0], w01 = wr[1], w02 = wr[2];
        float w10 = wr[3], w11 = wr[4], w12 = wr[5];
        float w20 = wr[6], w21 = wr[7], w22 = wr[8];
        const float* l0 = &Ls[(ic * 3 + 0) * 66 + xg];
        const float* l1 = &Ls[(ic * 3 + 1) * 66 + xg];
        const float* l2 = &Ls[(ic * 3 + 2) * 66 + xg];
        float a0 = l0[0], a1 = l0[1], a2 = l0[2], a3 = l0[3], a4 = l0[4], a5 = l0[5];
        float b0 = l1[0], b1 = l1[1], b2 = l1[2], b3 = l1[3], b4 = l1[4], b5 = l1[5];
        float c0 = l2[0], c1 = l2[1], c2 = l2[2], c3 = l2[3], c4 = l2[4], c5 = l2[5];
        acc0 += a0*w00 + a1*w01 + a2*w02 + b0*w10 + b1*w11 + b2*w12 + c0*w20 + c1*w21 + c2*w22;
        acc1 += a1*w00 + a2*w01 + a3*w02 + b1*w10 + b2*w11 + b3*w12 + c1*w20 + c2*w21 + c3*w22;
        acc2 += a2*w00 + a3*w01 + a4*w02 + b2*w10 + b3*w11 + b4*w12 + c2*w20 + c3*w21 + c4*w22;
        acc3 += a3*w00 + a4*w01 + a5*w02 + b3*w10 + b4*w11 + b5*w12 + c3*w20 + c4*w21 + c5*w22;
    }
    float* op = out + (((size_t)(b * 16 + oc) * 64 + y) * 64 + xg);
    op[0] = fmaxf(acc0, 0.f);
    op[1] = fmaxf(acc1, 0.f);
    op[2] = fmaxf(acc2, 0.f);
    op[3] = fmaxf(acc3, 0.f);
}

// ------- conv2: 16->3, 3x3, pad1 -------
__global__ __launch_bounds__(256) void conv2_kernel(const float* __restrict__ in,
                                                    const float* __restrict__ w,
                                                    const float* __restrict__ bias,
                                                    float* __restrict__ out) {
    __shared__ float Ls[16 * 3 * 66];
    __shared__ float Ws[3 * 160];
    int tid = threadIdx.x;
    int y = blockIdx.x, b = blockIdx.y;
    for (int i = tid; i < 432; i += 256) {
        int oc = i / 144, rem = i % 144;
        Ws[oc * 160 + rem] = w[i];
    }
    for (int i = tid; i < 3072; i += 256) {
        int r = i >> 6, x = i & 63;
        int ic = r / 3, ky = r % 3;
        int yy = y + ky - 1;
        float v = (yy >= 0 && yy < 64) ? in[((size_t)(b * 16 + ic) * 64 + yy) * 64 + x] : 0.f;
        Ls[(ic * 3 + ky) * 66 + x + 1] = v;
        if (x == 0)  Ls[(ic * 3 + ky) * 66 + 0]  = 0.f;
        if (x == 63) Ls[(ic * 3 + ky) * 66 + 65] = 0.f;
    }
    __syncthreads();
    int oc = tid >> 6, x = tid & 63;
    if (oc < 3) {
        float acc = bias[oc];
        for (int ic = 0; ic < 16; ic++) {
            const float* wr = &Ws[oc * 160 + ic * 9];
            const float* l0 = &Ls[(ic * 3 + 0) * 66 + x];
            const float* l1 = &Ls[(ic * 3 + 1) * 66 + x];
            const float* l2 = &Ls[(ic * 3 + 2) * 66 + x];
            acc += l0[0]*wr[0] + l0[1]*wr[1] + l0[2]*wr[2]
                 + l1[0]*wr[3] + l1[1]*wr[4] + l1[2]*wr[5]
                 + l2[0]*wr[6] + l2[1]*wr[7] + l2[2]*wr[8];
        }
        out[((size_t)(b * 3 + oc) * 64 + y) * 64 + x] = acc;
    }
}

// ---------------- launch ----------------
extern "C" void kernel_launch(void* const* d_in, const int* in_sizes, int n_in,
                              void* d_out, int out_size, void* d_ws, size_t ws_size,
                              hipStream_t stream) {
    const float* x_in   = (const float*)d_in[0];
    const float* qkv_w  = (const float*)d_in[1];
    const float* qkv_b  = (const float*)d_in[2];
    const float* proj_w = (const float*)d_in[3];
    const float* proj_b = (const float*)d_in[4];
    const float* nq_g   = (const float*)d_in[5];
    const float* nq_b   = (const float*)d_in[6];
    const float* nk_g   = (const float*)d_in[7];
    const float* nk_b   = (const float*)d_in[8];
    const float* n1_g   = (const float*)d_in[9];
    const float* n1_b   = (const float*)d_in[10];
    const float* n2_g   = (const float*)d_in[11];
    const float* n2_b   = (const float*)d_in[12];
    const float* fc1_w  = (const float*)d_in[13];
    const float* fc1_b  = (const float*)d_in[14];
    const float* fc2_w  = (const float*)d_in[15];
    const float* fc2_b  = (const float*)d_in[16];
    const float* fin_w  = (const float*)d_in[17];
    const float* fin_b  = (const float*)d_in[18];
    const float* c1_w   = (const float*)d_in[19];
    const float* c1_b   = (const float*)d_in[20];
    const float* c2_w   = (const float*)d_in[21];
    const float* c2_b   = (const float*)d_in[22];
    float* out = (float*)d_out;

    char* w = (char*)d_ws;
    float* xb           = (float*)w;          w += (size_t)2 * 1024 * 1024 * 4;
    unsigned short* hnb = (unsigned short*)w; w += (size_t)2 * 1024 * 1024 * 2;
    float* qkv          = (float*)w;          w += (size_t)2 * 1024 * 3072 * 4;
    unsigned short* obb = (unsigned short*)w; w += (size_t)2 * 1024 * 1024 * 2;
    unsigned short* mhb = (unsigned short*)w; w += (size_t)2 * 1024 * 4096 * 2;
    float* xf           = (float*)w;          w += (size_t)2 * 1024 * 256 * 4;
    float* img          = (float*)w;          w += (size_t)2 * 64 * 64 * 64 * 4;
    float* c1o          = (float*)w;          w += (size_t)2 * 16 * 64 * 64 * 4;
    unsigned short* Qb  = (unsigned short*)w; w += (size_t)2 * 1024 * 1024 * 2;
    unsigned short* Kb  = (unsigned short*)w; w += (size_t)2 * 1024 * 1024 * 2;
    unsigned short* Vt  = (unsigned short*)w; w += (size_t)2 * 16 * 64 * 1024 * 2;
    float* skb          = (float*)w;          w += (size_t)2 * 2048 * 1024 * 4;   // split-K partials
    unsigned short* WQ  = (unsigned short*)w; w += (size_t)4 * 1024 * 3072 * 2;
    unsigned short* WP  = (unsigned short*)w; w += (size_t)4 * 1024 * 1024 * 2;
    unsigned short* W1  = (unsigned short*)w; w += (size_t)4 * 1024 * 4096 * 2;
    unsigned short* W2  = (unsigned short*)w; w += (size_t)4 * 4096 * 1024 * 2;
    unsigned short* WF  = (unsigned short*)w; w += (size_t)1024 * 256 * 2;

    wtrans_kernel<<<dim3(48, 16, 4), 256, 0, stream>>>(qkv_w, WQ, 1024, 3072);
    wtrans_kernel<<<dim3(16, 16, 4), 256, 0, stream>>>(proj_w, WP, 1024, 1024);
    wtrans_kernel<<<dim3(64, 16, 4), 256, 0, stream>>>(fc1_w, W1, 1024, 4096);
    wtrans_kernel<<<dim3(16, 64, 4), 256, 0, stream>>>(fc2_w, W2, 4096, 1024);
    wtrans_kernel<<<dim3(4, 16, 1), 256, 0, stream>>>(fin_w, WF, 1024, 256);

    posembed_kernel<<<8192, 256, 0, stream>>>(x_in, xb);

    for (int i = 0; i < 4; i++) {
        ln_kernel<<<2048, 256, 0, stream>>>(xb, hnb, n1_g + i * 1024, n1_b + i * 1024, 1e-5f, 1);
        gemm_bf16<128, 128, 2, 2, 0, false, false, false><<<dim3(24, 16), 256, 0, stream>>>(
            hnb, WQ + (size_t)i * 3072 * 1024, qkv_b + i * 3072, qkv, nullptr, 2048, 3072, 1024, 1024);
        qkvprep_kernel<<<dim3(16, 16, 2), 256, 0, stream>>>(
            qkv, nq_g + i * 64, nq_b + i * 64, nk_g + i * 64, nk_b + i * 64, Qb, Kb, Vt);
        attn_mfma<<<dim3(16, 16, 2), 256, 0, stream>>>(Qb, Kb, Vt, obb);
        gemm_bf16<64, 128, 2, 2, 0, true, false, false><<<dim3(8, 32), 256, 0, stream>>>(
            obb, WP + (size_t)i * 1024 * 1024, proj_b + i * 1024, xb, nullptr, 2048, 1024, 1024, 1024);
        ln_kernel<<<2048, 256, 0, stream>>>(xb, hnb, n2_g + i * 1024, n2_b + i * 1024, 1e-5f, 1);
        gemm_bf16<128, 128, 2, 2, 1, false, true, false><<<dim3(32, 16), 256, 0, stream>>>(
            hnb, W1 + (size_t)i * 4096 * 1024, fc1_b + i * 4096, nullptr, mhb, 2048, 4096, 1024, 1024);
        gemm_bf16<128, 128, 2, 2, 0, false, false, true><<<dim3(8, 16, 2), 256, 0, stream>>>(
            mhb, W2 + (size_t)i * 1024 * 4096, fc2_b + i * 1024, skb, nullptr, 2048, 1024, 2048, 4096);
        skreduce_kernel<<<2048, 256, 0, stream>>>(skb, fc2_b + i * 1024, xb);
    }

    ln_kernel<<<2048, 256, 0, stream>>>(xb, hnb, nullptr, nullptr, 1e-6f, 0);
    gemm_bf16<64, 64, 2, 2, 0, false, false, false><<<dim3(4, 32), 256, 0, stream>>>(
        hnb, WF, fin_b, xf, nullptr, 2048, 256, 1024, 1024);
    unpatchify_kernel<<<2048, 256, 0, stream>>>(xf, img);
    conv1_kernel<<<dim3(64, 2), 256, 0, stream>>>(img, c1_w, c1_b, c1o);
    conv2_kernel<<<dim3(64, 2), 256, 0, stream>>>(c1o, c2_w, c2_b, out);
}

// Round 4
// 985.996 us; speedup vs baseline: 1.2378x; 1.2378x over previous
//
#include <hip/hip_runtime.h>
#include <hip/hip_bf16.h>
#include <math.h>

typedef float floatx4 __attribute__((ext_vector_type(4)));
typedef short bf16x8 __attribute__((ext_vector_type(8)));   // 8 bf16 in 4 VGPRs

__device__ __forceinline__ unsigned short f2bf(float x) {
    union { float f; unsigned int u; } v; v.f = x;
    unsigned int r = v.u + 0x7fffu + ((v.u >> 16) & 1u);    // RNE
    return (unsigned short)(r >> 16);
}

__device__ __forceinline__ void load_lds16(const void* g, void* l) {
    __builtin_amdgcn_global_load_lds(
        (const __attribute__((address_space(1))) unsigned int*)(uintptr_t)g,
        (__attribute__((address_space(3))) unsigned int*)(uintptr_t)l, 16, 0, 0);
}

// ---------------- pos embed + input add (float math: |err| ~1e-6 << bf16 noise) ----
__global__ void posembed_kernel(const float* __restrict__ xin, float* __restrict__ xb) {
    int idx = blockIdx.x * 256 + threadIdx.x;     // 2*1024*1024
    int c = idx & 1023;
    int n = (idx >> 10) & 1023;
    int pos = (c < 512) ? (n & 31) : (n >> 5);
    int cc = c & 511;
    int k = cc & 255;
    float om = expf(-(float)k * (9.210340371976184f / 256.0f));
    float arg = (float)pos * om;
    float e = (cc < 256) ? sinf(arg) : cosf(arg);
    xb[idx] = xin[idx] + e;
}

// ---------------- layernorm over C=1024, bf16 output ----------------
__global__ __launch_bounds__(256) void ln_kernel(const float* __restrict__ X,
                                                 unsigned short* __restrict__ Y,
                                                 const float* __restrict__ g,
                                                 const float* __restrict__ b,
                                                 float eps, int affine) {
    int row = blockIdx.x;
    const float4* xr = (const float4*)(X + (size_t)row * 1024);
    float4 x = xr[threadIdx.x];
    float s = x.x + x.y + x.z + x.w;
    float sq = x.x * x.x + x.y * x.y + x.z * x.z + x.w * x.w;
    __shared__ float red[8];
    #pragma unroll
    for (int off = 32; off; off >>= 1) { s += __shfl_xor(s, off); sq += __shfl_xor(sq, off); }
    int wid = threadIdx.x >> 6, lane = threadIdx.x & 63;
    if (!lane) { red[wid] = s; red[wid + 4] = sq; }
    __syncthreads();
    s = red[0] + red[1] + red[2] + red[3];
    sq = red[4] + red[5] + red[6] + red[7];
    float mu = s * (1.f / 1024.f);
    float var = sq * (1.f / 1024.f) - mu * mu;
    float rs = rsqrtf(var + eps);
    int c = threadIdx.x * 4;
    float4 y;
    if (affine) {
        y.x = (x.x - mu) * rs * g[c + 0] + b[c + 0];
        y.y = (x.y - mu) * rs * g[c + 1] + b[c + 1];
        y.z = (x.z - mu) * rs * g[c + 2] + b[c + 2];
        y.w = (x.w - mu) * rs * g[c + 3] + b[c + 3];
    } else {
        y.x = (x.x - mu) * rs; y.y = (x.y - mu) * rs;
        y.z = (x.z - mu) * rs; y.w = (x.w - mu) * rs;
    }
    ushort4 o;
    o.x = f2bf(y.x); o.y = f2bf(y.y); o.z = f2bf(y.z); o.w = f2bf(y.w);
    *(ushort4*)(Y + (size_t)row * 1024 + c) = o;
}

// ---- merged qk-norm + V transpose: one pass over qkv ----
__global__ __launch_bounds__(256) void qkvprep_kernel(const float* __restrict__ qkv,
                                                      const float* __restrict__ nqg,
                                                      const float* __restrict__ nqb,
                                                      const float* __restrict__ nkg,
                                                      const float* __restrict__ nkb,
                                                      unsigned short* __restrict__ Qb,
                                                      unsigned short* __restrict__ Kb,
                                                      unsigned short* __restrict__ Vt) {
    __shared__ float t[64][65];
    int tid = threadIdx.x;
    int l0 = blockIdx.x * 64, h = blockIdx.y, b = blockIdx.z;
    for (int i = tid; i < 4096; i += 256) {
        int lr = i >> 6, dd = i & 63;
        t[lr][dd] = qkv[((size_t)(b * 1024 + l0 + lr)) * 3072 + 2048 + h * 64 + dd];
    }
    __syncthreads();
    for (int i = tid; i < 4096; i += 256) {
        int dd = i >> 6, lc = i & 63;
        Vt[((size_t)((b * 16 + h) * 64 + dd)) * 1024 + l0 + lc] = f2bf(t[lc][dd]);
    }
    int wave = tid >> 6, lane = tid & 63;
    float gq = nqg[lane], bq = nqb[lane], gk = nkg[lane], bk = nkb[lane];
    for (int i = 0; i < 16; i++) {
        int l = l0 + wave + 4 * i;
        const float* base = qkv + (size_t)(b * 1024 + l) * 3072 + h * 64 + lane;
        #pragma unroll
        for (int part = 0; part < 2; part++) {
            float v = base[part * 1024];
            float s = v, sq = v * v;
            #pragma unroll
            for (int off = 32; off; off >>= 1) { s += __shfl_xor(s, off); sq += __shfl_xor(sq, off); }
            float mu = s * (1.f / 64.f);
            float var = sq * (1.f / 64.f) - mu * mu;
            float rs = rsqrtf(var + 1e-5f);
            float y = (v - mu) * rs * (part ? gk : gq) + (part ? bk : bq);
            unsigned short* dst = part ? Kb : Qb;
            dst[(size_t)(b * 1024 + l) * 1024 + h * 64 + lane] = f2bf(y * (part ? 1.f : 0.125f));
        }
    }
}

// ---- MFMA flash attention: block = (64 q-rows, head, b); 4 waves x 16 rows ----
// XOR-swizzled K/V LDS staging (R1-verified) + 2-phase double buffer with
// counted vmcnt: next chunk's global_load_lds issued before waiting, wait is
// vmcnt(4) (this wave's 4 next-loads outstanding) -> current chunk's loads,
// issued a full chunk earlier, are already complete. Never vmcnt(0) mid-loop.
__global__ __launch_bounds__(256) void attn_mfma(const unsigned short* __restrict__ Qb,
                                                 const unsigned short* __restrict__ Kb,
                                                 const unsigned short* __restrict__ Vt,
                                                 unsigned short* __restrict__ ob) {
    __shared__ short Ks[2][64 * 64];
    __shared__ short Vs[2][64 * 64];
    __shared__ short Pl[4][16 * 72];
    int tid = threadIdx.x;
    int lane = tid & 63, wave = tid >> 6;
    int ln16 = lane & 15, q = lane >> 4;
    int b = blockIdx.z, h = blockIdx.y, q0 = blockIdx.x * 64;
    int sw = ln16 & 7;                       // read-side chunk swizzle (row&7 == ln16&7)
    int rc0 = (q ^ sw) * 8;                  // chunk offsets for the two K-halves
    int rc1 = ((4 + q) ^ sw) * 8;

    const unsigned short* qrow = Qb + ((size_t)(b * 1024 + q0 + wave * 16 + ln16)) * 1024 + h * 64;
    bf16x8 qf0 = *(const bf16x8*)(qrow + q * 8);
    bf16x8 qf1 = *(const bf16x8*)(qrow + 32 + q * 8);

    floatx4 o[4];
    #pragma unroll
    for (int td = 0; td < 4; td++) o[td] = (floatx4){0.f, 0.f, 0.f, 0.f};
    float mrow[4] = {-1e30f, -1e30f, -1e30f, -1e30f};
    float lrow[4] = {0.f, 0.f, 0.f, 0.f};

    const unsigned short* kbase0 = Kb + ((size_t)(b * 1024)) * 1024 + h * 64;
    const unsigned short* vbase0 = Vt + ((size_t)((b * 16 + h) * 64)) * 1024;

    // stage one 64-row K/V chunk into buffer `bi` (4 loads/thread, src pre-swizzled)
    auto stage = [&](int bi, int l0) {
        #pragma unroll
        for (int it = 0; it < 2; it++) {
            int j = tid + it * 256;
            int row = j >> 3, g = j & 7, gc = g ^ (row & 7);
            load_lds16(kbase0 + (size_t)(l0 + row) * 1024 + gc * 8, &Ks[bi][j * 8]);
            load_lds16(vbase0 + (size_t)row * 1024 + l0 + gc * 8, &Vs[bi][j * 8]);
        }
    };

    stage(0, 0);
    for (int ch = 0; ch < 16; ch++) {
        int cur = ch & 1;
        // WAR: all waves finished reading buf[cur^1] (prev iteration's compute)
        __builtin_amdgcn_s_barrier();
        if (ch < 15) {
            stage(cur ^ 1, (ch + 1) * 64);
            asm volatile("s_waitcnt vmcnt(4)" ::: "memory");   // cur loads done; next in flight
        } else {
            asm volatile("s_waitcnt vmcnt(0)" ::: "memory");
        }
        __builtin_amdgcn_s_barrier();        // cur buffer visible to all waves
        __builtin_amdgcn_sched_barrier(0);

        floatx4 s[4];
        #pragma unroll
        for (int t = 0; t < 4; t++) {
            s[t] = (floatx4){0.f, 0.f, 0.f, 0.f};
            int kr = (t * 16 + ln16) * 64;
            bf16x8 kf0 = *(const bf16x8*)&Ks[cur][kr + rc0];
            bf16x8 kf1 = *(const bf16x8*)&Ks[cur][kr + rc1];
            s[t] = __builtin_amdgcn_mfma_f32_16x16x32_bf16(qf0, kf0, s[t], 0, 0, 0);
            s[t] = __builtin_amdgcn_mfma_f32_16x16x32_bf16(qf1, kf1, s[t], 0, 0, 0);
        }
        float cm[4], rs[4], p[4][4];
        #pragma unroll
        for (int r = 0; r < 4; r++)
            cm[r] = fmaxf(fmaxf(s[0][r], s[1][r]), fmaxf(s[2][r], s[3][r]));
        #pragma unroll
        for (int off = 1; off < 16; off <<= 1) {
            #pragma unroll
            for (int r = 0; r < 4; r++) cm[r] = fmaxf(cm[r], __shfl_xor(cm[r], off));
        }
        #pragma unroll
        for (int r = 0; r < 4; r++) {
            float mnew = fmaxf(mrow[r], cm[r]);
            float alpha = __expf(mrow[r] - mnew);
            mrow[r] = mnew;
            rs[r] = 0.f;
            #pragma unroll
            for (int t = 0; t < 4; t++) {
                p[t][r] = __expf(s[t][r] - mnew);
                rs[r] += p[t][r];
            }
            lrow[r] *= alpha;
            #pragma unroll
            for (int td = 0; td < 4; td++) o[td][r] *= alpha;
        }
        #pragma unroll
        for (int off = 1; off < 16; off <<= 1) {
            #pragma unroll
            for (int r = 0; r < 4; r++) rs[r] += __shfl_xor(rs[r], off);
        }
        #pragma unroll
        for (int r = 0; r < 4; r++) lrow[r] += rs[r];

        // Pl[wave] is written and read by the SAME wave only: no barrier needed.
        short* pw = &Pl[wave][0];
        #pragma unroll
        for (int t = 0; t < 4; t++)
            #pragma unroll
            for (int r = 0; r < 4; r++)
                pw[(q * 4 + r) * 72 + t * 16 + ln16] = (short)f2bf(p[t][r]);
        bf16x8 pf0 = *(const bf16x8*)&pw[ln16 * 72 + q * 8];
        bf16x8 pf1 = *(const bf16x8*)&pw[ln16 * 72 + 32 + q * 8];
        #pragma unroll
        for (int td = 0; td < 4; td++) {
            int vr = (td * 16 + ln16) * 64;
            bf16x8 vf0 = *(const bf16x8*)&Vs[cur][vr + rc0];
            bf16x8 vf1 = *(const bf16x8*)&Vs[cur][vr + rc1];
            o[td] = __builtin_amdgcn_mfma_f32_16x16x32_bf16(pf0, vf0, o[td], 0, 0, 0);
            o[td] = __builtin_amdgcn_mfma_f32_16x16x32_bf16(pf1, vf1, o[td], 0, 0, 0);
        }
    }
    #pragma unroll
    for (int td = 0; td < 4; td++) {
        #pragma unroll
        for (int r = 0; r < 4; r++) {
            int row = q0 + wave * 16 + q * 4 + r;
            int col = h * 64 + td * 16 + ln16;
            ob[((size_t)(b * 1024 + row)) * 1024 + col] = f2bf(o[td][r] / lrow[r]);
        }
    }
}

// ------- batched weight transpose + bf16: in fp32 [z][K][N] -> out bf16 [z][N][K] ----
__global__ __launch_bounds__(256) void wtrans_kernel(const float* __restrict__ in,
                                                     unsigned short* __restrict__ out,
                                                     int K, int N) {
    __shared__ float t[64][65];
    int n0 = blockIdx.x * 64, k0 = blockIdx.y * 64, z = blockIdx.z;
    in  += (size_t)z * K * N;
    out += (size_t)z * N * K;
    for (int i = threadIdx.x; i < 4096; i += 256) {
        int kr = i >> 6, nc = i & 63;
        t[kr][nc] = in[(size_t)(k0 + kr) * N + n0 + nc];
    }
    __syncthreads();
    for (int i = threadIdx.x; i < 4096; i += 256) {
        int nr = i >> 6, kc = i & 63;
        out[(size_t)(n0 + nr) * K + k0 + kc] = f2bf(t[kc][nr]);
    }
}

// ------- bf16 MFMA GEMM, BK=64, XOR-swizzled LDS -------------------------------
// C = act(A@B + bias)[+C]; A[M][lda] bf16, Bt[N][lda] bf16.
// SPLITK: blockIdx.z selects K-chunk of size K; raw partials to Cf + z*M*N.
template <int BM, int BN, int WM, int WN, int ACT, bool ADDC, bool OUTBF16, bool SPLITK>
__global__ __launch_bounds__(256) void gemm_bf16(const unsigned short* __restrict__ A,
                                                 const unsigned short* __restrict__ Bt,
                                                 const float* __restrict__ bias,
                                                 float* __restrict__ Cf,
                                                 unsigned short* __restrict__ Cb,
                                                 int M, int N, int K, int lda) {
    constexpr int MT = BM / (WM * 16);
    constexpr int NT = BN / (WN * 16);
    __shared__ short As[BM * 64];
    __shared__ short Bs[BN * 64];
    int tid = threadIdx.x;
    int lane = tid & 63, wave = tid >> 6;
    int wm = wave / WN, wn = wave % WN;
    int ln16 = lane & 15, q = lane >> 4;
    int m0 = blockIdx.y * BM, n0 = blockIdx.x * BN;
    int kOff = SPLITK ? blockIdx.z * K : 0;

    floatx4 acc[MT][NT];
    #pragma unroll
    for (int i = 0; i < MT; i++)
        #pragma unroll
        for (int j = 0; j < NT; j++) acc[i][j] = (floatx4){0.f, 0.f, 0.f, 0.f};

    int kSteps = K >> 6;
    for (int ks = 0; ks < kSteps; ks++) {
        int k0 = kOff + (ks << 6);
        #pragma unroll
        for (int it = 0; it < BM / 32; it++) {
            int i = tid + it * 256;
            int row = i >> 3, gc = (i & 7) ^ (row & 7);   // XOR chunk swizzle
            load_lds16(A + (size_t)(m0 + row) * lda + k0 + gc * 8, &As[i * 8]);
        }
        #pragma unroll
        for (int it = 0; it < BN / 32; it++) {
            int i = tid + it * 256;
            int row = i >> 3, gc = (i & 7) ^ (row & 7);
            load_lds16(Bt + (size_t)(n0 + row) * lda + k0 + gc * 8, &Bs[i * 8]);
        }
        __syncthreads();
        bf16x8 af[2][MT], bf[2][NT];
        #pragma unroll
        for (int h = 0; h < 2; h++) {
            #pragma unroll
            for (int mi = 0; mi < MT; mi++) {
                int row = wm * (BM / WM) + mi * 16 + ln16;
                af[h][mi] = *(const bf16x8*)&As[row * 64 + (((h * 4 + q) ^ (row & 7)) * 8)];
            }
            #pragma unroll
            for (int ni = 0; ni < NT; ni++) {
                int row = wn * (BN / WN) + ni * 16 + ln16;
                bf[h][ni] = *(const bf16x8*)&Bs[row * 64 + (((h * 4 + q) ^ (row & 7)) * 8)];
            }
        }
        #pragma unroll
        for (int h = 0; h < 2; h++)
            #pragma unroll
            for (int mi = 0; mi < MT; mi++)
                #pragma unroll
                for (int ni = 0; ni < NT; ni++)
                    acc[mi][ni] = __builtin_amdgcn_mfma_f32_16x16x32_bf16(af[h][mi], bf[h][ni], acc[mi][ni], 0, 0, 0);
        __syncthreads();
    }

    int q4 = q * 4;
    float* Cp = SPLITK ? (Cf + (size_t)blockIdx.z * M * N) : Cf;
    #pragma unroll
    for (int ni = 0; ni < NT; ni++) {
        int col = n0 + wn * (BN / WN) + ni * 16 + ln16;
        float bv = SPLITK ? 0.f : bias[col];
        #pragma unroll
        for (int mi = 0; mi < MT; mi++) {
            #pragma unroll
            for (int r = 0; r < 4; r++) {
                int row = m0 + wm * (BM / WM) + mi * 16 + q4 + r;
                size_t off = (size_t)row * N + col;
                float v = acc[mi][ni][r] + bv;
                if (!SPLITK && ACT == 1) v = 0.5f * v * (1.f + erff(v * 0.70710678118654752f));
                if (!SPLITK && ADDC) v += Cf[off];
                if (!SPLITK && OUTBF16) Cb[off] = f2bf(v);
                else Cp[off] = v;
            }
        }
    }
}

// ------- split-K reduce: xb += P0 + P1 + bias (fc2 epilogue) -------
__global__ __launch_bounds__(256) void skreduce_kernel(const float* __restrict__ P,
                                                       const float* __restrict__ bias,
                                                       float* __restrict__ xb) {
    int idx = blockIdx.x * 256 + threadIdx.x;          // float4 index, 2048*1024/4
    float4 a = ((const float4*)P)[idx];
    float4 b = ((const float4*)P)[idx + 524288];
    float4 x = ((float4*)xb)[idx];
    const float4 bb = *(const float4*)(bias + (idx & 255) * 4);
    x.x += a.x + b.x + bb.x;
    x.y += a.y + b.y + bb.y;
    x.z += a.z + b.z + bb.z;
    x.w += a.w + b.w + bb.w;
    ((float4*)xb)[idx] = x;
}

// ---------------- unpatchify ----------------
__global__ void unpatchify_kernel(const float* __restrict__ xf, float* __restrict__ img) {
    int idx = blockIdx.x * 256 + threadIdx.x;
    int x = idx & 63, y = (idx >> 6) & 63, ch = (idx >> 12) & 63, b = idx >> 18;
    int hh = y >> 1, ww = x >> 1, p = y & 1, qq = x & 1;
    img[idx] = xf[((size_t)b * 1024 + hh * 32 + ww) * 256 + ch * 4 + p * 2 + qq];
}

// ------- conv1: 64->16, 3x3, pad1, relu -------
__global__ __launch_bounds__(256) void conv1_kernel(const float* __restrict__ img,
                                                    const float* __restrict__ w,
                                                    const float* __restrict__ bias,
                                                    float* __restrict__ out) {
    __shared__ float Ls[64 * 3 * 66];
    __shared__ float Ws[16 * 580];
    int tid = threadIdx.x;
    int y = blockIdx.x, b = blockIdx.y;
    for (int i = tid; i < 9216; i += 256) {
        int oc = i / 576, rem = i % 576;
        Ws[oc * 580 + rem] = w[i];
    }
    for (int i = tid; i < 12288; i += 256) {
        int r = i >> 6, x = i & 63;
        int ic = r / 3, ky = r % 3;
        int yy = y + ky - 1;
        float v = (yy >= 0 && yy < 64) ? img[((size_t)(b * 64 + ic) * 64 + yy) * 64 + x] : 0.f;
        Ls[(ic * 3 + ky) * 66 + x + 1] = v;
        if (x == 0)  Ls[(ic * 3 + ky) * 66 + 0]  = 0.f;
        if (x == 63) Ls[(ic * 3 + ky) * 66 + 65] = 0.f;
    }
    __syncthreads();
    int oc = tid >> 4, xg = (tid & 15) * 4;
    float bv = bias[oc];
    float acc0 = bv, acc1 = bv, acc2 = bv, acc3 = bv;
    for (int ic = 0; ic < 64; ic++) {
        const float* wr = &Ws[oc * 580 + ic * 9];
        float w00 = wr[0], w01 = wr[1], w02 = wr[2];
        float w10 = wr[3], w11 = wr[4], w12 = wr[5];
        float w20 = wr[6], w21 = wr[7], w22 = wr[8];
        const float* l0 = &Ls[(ic * 3 + 0) * 66 + xg];
        const float* l1 = &Ls[(ic * 3 + 1) * 66 + xg];
        const float* l2 = &Ls[(ic * 3 + 2) * 66 + xg];
        float a0 = l0[0], a1 = l0[1], a2 = l0[2], a3 = l0[3], a4 = l0[4], a5 = l0[5];
        float b0 = l1[0], b1 = l1[1], b2 = l1[2], b3 = l1[3], b4 = l1[4], b5 = l1[5];
        float c0 = l2[0], c1 = l2[1], c2 = l2[2], c3 = l2[3], c4 = l2[4], c5 = l2[5];
        acc0 += a0*w00 + a1*w01 + a2*w02 + b0*w10 + b1*w11 + b2*w12 + c0*w20 + c1*w21 + c2*w22;
        acc1 += a1*w00 + a2*w01 + a3*w02 + b1*w10 + b2*w11 + b3*w12 + c1*w20 + c2*w21 + c3*w22;
        acc2 += a2*w00 + a3*w01 + a4*w02 + b2*w10 + b3*w11 + b4*w12 + c2*w20 + c3*w21 + c4*w22;
        acc3 += a3*w00 + a4*w01 + a5*w02 + b3*w10 + b4*w11 + b5*w12 + c3*w20 + c4*w21 + c5*w22;
    }
    float* op = out + (((size_t)(b * 16 + oc) * 64 + y) * 64 + xg);
    op[0] = fmaxf(acc0, 0.f);
    op[1] = fmaxf(acc1, 0.f);
    op[2] = fmaxf(acc2, 0.f);
    op[3] = fmaxf(acc3, 0.f);
}

// ------- conv2: 16->3, 3x3, pad1 -------
__global__ __launch_bounds__(256) void conv2_kernel(const float* __restrict__ in,
                                                    const float* __restrict__ w,
                                                    const float* __restrict__ bias,
                                                    float* __restrict__ out) {
    __shared__ float Ls[16 * 3 * 66];
    __shared__ float Ws[3 * 160];
    int tid = threadIdx.x;
    int y = blockIdx.x, b = blockIdx.y;
    for (int i = tid; i < 432; i += 256) {
        int oc = i / 144, rem = i % 144;
        Ws[oc * 160 + rem] = w[i];
    }
    for (int i = tid; i < 3072; i += 256) {
        int r = i >> 6, x = i & 63;
        int ic = r / 3, ky = r % 3;
        int yy = y + ky - 1;
        float v = (yy >= 0 && yy < 64) ? in[((size_t)(b * 16 + ic) * 64 + yy) * 64 + x] : 0.f;
        Ls[(ic * 3 + ky) * 66 + x + 1] = v;
        if (x == 0)  Ls[(ic * 3 + ky) * 66 + 0]  = 0.f;
        if (x == 63) Ls[(ic * 3 + ky) * 66 + 65] = 0.f;
    }
    __syncthreads();
    int oc = tid >> 6, x = tid & 63;
    if (oc < 3) {
        float acc = bias[oc];
        for (int ic = 0; ic < 16; ic++) {
            const float* wr = &Ws[oc * 160 + ic * 9];
            const float* l0 = &Ls[(ic * 3 + 0) * 66 + x];
            const float* l1 = &Ls[(ic * 3 + 1) * 66 + x];
            const float* l2 = &Ls[(ic * 3 + 2) * 66 + x];
            acc += l0[0]*wr[0] + l0[1]*wr[1] + l0[2]*wr[2]
                 + l1[0]*wr[3] + l1[1]*wr[4] + l1[2]*wr[5]
                 + l2[0]*wr[6] + l2[1]*wr[7] + l2[2]*wr[8];
        }
        out[((size_t)(b * 3 + oc) * 64 + y) * 64 + x] = acc;
    }
}

// ---------------- launch ----------------
extern "C" void kernel_launch(void* const* d_in, const int* in_sizes, int n_in,
                              void* d_out, int out_size, void* d_ws, size_t ws_size,
                              hipStream_t stream) {
    const float* x_in   = (const float*)d_in[0];
    const float* qkv_w  = (const float*)d_in[1];
    const float* qkv_b  = (const float*)d_in[2];
    const float* proj_w = (const float*)d_in[3];
    const float* proj_b = (const float*)d_in[4];
    const float* nq_g   = (const float*)d_in[5];
    const float* nq_b   = (const float*)d_in[6];
    const float* nk_g   = (const float*)d_in[7];
    const float* nk_b   = (const float*)d_in[8];
    const float* n1_g   = (const float*)d_in[9];
    const float* n1_b   = (const float*)d_in[10];
    const float* n2_g   = (const float*)d_in[11];
    const float* n2_b   = (const float*)d_in[12];
    const float* fc1_w  = (const float*)d_in[13];
    const float* fc1_b  = (const float*)d_in[14];
    const float* fc2_w  = (const float*)d_in[15];
    const float* fc2_b  = (const float*)d_in[16];
    const float* fin_w  = (const float*)d_in[17];
    const float* fin_b  = (const float*)d_in[18];
    const float* c1_w   = (const float*)d_in[19];
    const float* c1_b   = (const float*)d_in[20];
    const float* c2_w   = (const float*)d_in[21];
    const float* c2_b   = (const float*)d_in[22];
    float* out = (float*)d_out;

    char* w = (char*)d_ws;
    float* xb           = (float*)w;          w += (size_t)2 * 1024 * 1024 * 4;
    unsigned short* hnb = (unsigned short*)w; w += (size_t)2 * 1024 * 1024 * 2;
    float* qkv          = (float*)w;          w += (size_t)2 * 1024 * 3072 * 4;
    unsigned short* obb = (unsigned short*)w; w += (size_t)2 * 1024 * 1024 * 2;
    unsigned short* mhb = (unsigned short*)w; w += (size_t)2 * 1024 * 4096 * 2;
    float* xf           = (float*)w;          w += (size_t)2 * 1024 * 256 * 4;
    float* img          = (float*)w;          w += (size_t)2 * 64 * 64 * 64 * 4;
    float* c1o          = (float*)w;          w += (size_t)2 * 16 * 64 * 64 * 4;
    unsigned short* Qb  = (unsigned short*)w; w += (size_t)2 * 1024 * 1024 * 2;
    unsigned short* Kb  = (unsigned short*)w; w += (size_t)2 * 1024 * 1024 * 2;
    unsigned short* Vt  = (unsigned short*)w; w += (size_t)2 * 16 * 64 * 1024 * 2;
    float* skb          = (float*)w;          w += (size_t)2 * 2048 * 1024 * 4;   // split-K partials
    unsigned short* WQ  = (unsigned short*)w; w += (size_t)4 * 1024 * 3072 * 2;
    unsigned short* WP  = (unsigned short*)w; w += (size_t)4 * 1024 * 1024 * 2;
    unsigned short* W1  = (unsigned short*)w; w += (size_t)4 * 1024 * 4096 * 2;
    unsigned short* W2  = (unsigned short*)w; w += (size_t)4 * 4096 * 1024 * 2;
    unsigned short* WF  = (unsigned short*)w; w += (size_t)1024 * 256 * 2;

    wtrans_kernel<<<dim3(48, 16, 4), 256, 0, stream>>>(qkv_w, WQ, 1024, 3072);
    wtrans_kernel<<<dim3(16, 16, 4), 256, 0, stream>>>(proj_w, WP, 1024, 1024);
    wtrans_kernel<<<dim3(64, 16, 4), 256, 0, stream>>>(fc1_w, W1, 1024, 4096);
    wtrans_kernel<<<dim3(16, 64, 4), 256, 0, stream>>>(fc2_w, W2, 4096, 1024);
    wtrans_kernel<<<dim3(4, 16, 1), 256, 0, stream>>>(fin_w, WF, 1024, 256);

    posembed_kernel<<<8192, 256, 0, stream>>>(x_in, xb);

    for (int i = 0; i < 4; i++) {
        ln_kernel<<<2048, 256, 0, stream>>>(xb, hnb, n1_g + i * 1024, n1_b + i * 1024, 1e-5f, 1);
        gemm_bf16<64, 128, 2, 2, 0, false, false, false><<<dim3(24, 32), 256, 0, stream>>>(
            hnb, WQ + (size_t)i * 3072 * 1024, qkv_b + i * 3072, qkv, nullptr, 2048, 3072, 1024, 1024);
        qkvprep_kernel<<<dim3(16, 16, 2), 256, 0, stream>>>(
            qkv, nq_g + i * 64, nq_b + i * 64, nk_g + i * 64, nk_b + i * 64, Qb, Kb, Vt);
        attn_mfma<<<dim3(16, 16, 2), 256, 0, stream>>>(Qb, Kb, Vt, obb);
        gemm_bf16<64, 64, 2, 2, 0, true, false, false><<<dim3(16, 32), 256, 0, stream>>>(
            obb, WP + (size_t)i * 1024 * 1024, proj_b + i * 1024, xb, nullptr, 2048, 1024, 1024, 1024);
        ln_kernel<<<2048, 256, 0, stream>>>(xb, hnb, n2_g + i * 1024, n2_b + i * 1024, 1e-5f, 1);
        gemm_bf16<64, 128, 2, 2, 1, false, true, false><<<dim3(32, 32), 256, 0, stream>>>(
            hnb, W1 + (size_t)i * 4096 * 1024, fc1_b + i * 4096, nullptr, mhb, 2048, 4096, 1024, 1024);
        gemm_bf16<64, 64, 2, 2, 0, false, false, true><<<dim3(16, 32, 2), 256, 0, stream>>>(
            mhb, W2 + (size_t)i * 1024 * 4096, fc2_b + i * 1024, skb, nullptr, 2048, 1024, 2048, 4096);
        skreduce_kernel<<<2048, 256, 0, stream>>>(skb, fc2_b + i * 1024, xb);
    }

    ln_kernel<<<2048, 256, 0, stream>>>(xb, hnb, nullptr, nullptr, 1e-6f, 0);
    gemm_bf16<64, 64, 2, 2, 0, false, false, false><<<dim3(4, 32), 256, 0, stream>>>(
        hnb, WF, fin_b, xf, nullptr, 2048, 256, 1024, 1024);
    unpatchify_kernel<<<2048, 256, 0, stream>>>(xf, img);
    conv1_kernel<<<dim3(64, 2), 256, 0, stream>>>(img, c1_w, c1_b, c1o);
    conv2_kernel<<<dim3(64, 2), 256, 0, stream>>>(c1o, c2_w, c2_b, out);
}

// Round 7
// 965.737 us; speedup vs baseline: 1.2637x; 1.0210x over previous
//
#include <hip/hip_runtime.h>
#include <hip/hip_bf16.h>
#include <math.h>

typedef float floatx4 __attribute__((ext_vector_type(4)));
typedef short bf16x8 __attribute__((ext_vector_type(8)));   // 8 bf16 in 4 VGPRs

__device__ __forceinline__ unsigned short f2bf(float x) {
    union { float f; unsigned int u; } v; v.f = x;
    unsigned int r = v.u + 0x7fffu + ((v.u >> 16) & 1u);    // RNE
    return (unsigned short)(r >> 16);
}

__device__ __forceinline__ void load_lds16(const void* g, void* l) {
    __builtin_amdgcn_global_load_lds(
        (const __attribute__((address_space(1))) unsigned int*)(uintptr_t)g,
        (__attribute__((address_space(3))) unsigned int*)(uintptr_t)l, 16, 0, 0);
}

// ---------------- pos embed + input add (float math: |err| ~1e-6 << bf16 noise) ----
__global__ void posembed_kernel(const float* __restrict__ xin, float* __restrict__ xb) {
    int idx = blockIdx.x * 256 + threadIdx.x;     // 2*1024*1024
    int c = idx & 1023;
    int n = (idx >> 10) & 1023;
    int pos = (c < 512) ? (n & 31) : (n >> 5);
    int cc = c & 511;
    int k = cc & 255;
    float om = expf(-(float)k * (9.210340371976184f / 256.0f));
    float arg = (float)pos * om;
    float e = (cc < 256) ? sinf(arg) : cosf(arg);
    xb[idx] = xin[idx] + e;
}

// ---------------- layernorm over C=1024, bf16 output ----------------
__global__ __launch_bounds__(256) void ln_kernel(const float* __restrict__ X,
                                                 unsigned short* __restrict__ Y,
                                                 const float* __restrict__ g,
                                                 const float* __restrict__ b,
                                                 float eps, int affine) {
    int row = blockIdx.x;
    const float4* xr = (const float4*)(X + (size_t)row * 1024);
    float4 x = xr[threadIdx.x];
    float s = x.x + x.y + x.z + x.w;
    float sq = x.x * x.x + x.y * x.y + x.z * x.z + x.w * x.w;
    __shared__ float red[8];
    #pragma unroll
    for (int off = 32; off; off >>= 1) { s += __shfl_xor(s, off); sq += __shfl_xor(sq, off); }
    int wid = threadIdx.x >> 6, lane = threadIdx.x & 63;
    if (!lane) { red[wid] = s; red[wid + 4] = sq; }
    __syncthreads();
    s = red[0] + red[1] + red[2] + red[3];
    sq = red[4] + red[5] + red[6] + red[7];
    float mu = s * (1.f / 1024.f);
    float var = sq * (1.f / 1024.f) - mu * mu;
    float rs = rsqrtf(var + eps);
    int c = threadIdx.x * 4;
    float4 y;
    if (affine) {
        y.x = (x.x - mu) * rs * g[c + 0] + b[c + 0];
        y.y = (x.y - mu) * rs * g[c + 1] + b[c + 1];
        y.z = (x.z - mu) * rs * g[c + 2] + b[c + 2];
        y.w = (x.w - mu) * rs * g[c + 3] + b[c + 3];
    } else {
        y.x = (x.x - mu) * rs; y.y = (x.y - mu) * rs;
        y.z = (x.z - mu) * rs; y.w = (x.w - mu) * rs;
    }
    ushort4 o;
    o.x = f2bf(y.x); o.y = f2bf(y.y); o.z = f2bf(y.z); o.w = f2bf(y.w);
    *(ushort4*)(Y + (size_t)row * 1024 + c) = o;
}

// ---- merged qk-norm + V transpose: one pass over qkv ----
__global__ __launch_bounds__(256) void qkvprep_kernel(const float* __restrict__ qkv,
                                                      const float* __restrict__ nqg,
                                                      const float* __restrict__ nqb,
                                                      const float* __restrict__ nkg,
                                                      const float* __restrict__ nkb,
                                                      unsigned short* __restrict__ Qb,
                                                      unsigned short* __restrict__ Kb,
                                                      unsigned short* __restrict__ Vt) {
    __shared__ float t[64][65];
    int tid = threadIdx.x;
    int l0 = blockIdx.x * 64, h = blockIdx.y, b = blockIdx.z;
    for (int i = tid; i < 4096; i += 256) {
        int lr = i >> 6, dd = i & 63;
        t[lr][dd] = qkv[((size_t)(b * 1024 + l0 + lr)) * 3072 + 2048 + h * 64 + dd];
    }
    __syncthreads();
    for (int i = tid; i < 4096; i += 256) {
        int dd = i >> 6, lc = i & 63;
        Vt[((size_t)((b * 16 + h) * 64 + dd)) * 1024 + l0 + lc] = f2bf(t[lc][dd]);
    }
    int wave = tid >> 6, lane = tid & 63;
    float gq = nqg[lane], bq = nqb[lane], gk = nkg[lane], bk = nkb[lane];
    for (int i = 0; i < 16; i++) {
        int l = l0 + wave + 4 * i;
        const float* base = qkv + (size_t)(b * 1024 + l) * 3072 + h * 64 + lane;
        #pragma unroll
        for (int part = 0; part < 2; part++) {
            float v = base[part * 1024];
            float s = v, sq = v * v;
            #pragma unroll
            for (int off = 32; off; off >>= 1) { s += __shfl_xor(s, off); sq += __shfl_xor(sq, off); }
            float mu = s * (1.f / 64.f);
            float var = sq * (1.f / 64.f) - mu * mu;
            float rs = rsqrtf(var + 1e-5f);
            float y = (v - mu) * rs * (part ? gk : gq) + (part ? bk : bq);
            unsigned short* dst = part ? Kb : Qb;
            dst[(size_t)(b * 1024 + l) * 1024 + h * 64 + lane] = f2bf(y * (part ? 1.f : 0.125f));
        }
    }
}

// ---- MFMA flash attention: block = (64 q-rows, head, b); 4 waves x 16 rows ----
// XOR-swizzled K/V LDS staging + 2-phase double buffer with counted vmcnt
// (R4-verified): next chunk's global_load_lds issued before waiting, wait is
// vmcnt(4) -> current chunk's loads, issued a full chunk earlier, are done.
__global__ __launch_bounds__(256) void attn_mfma(const unsigned short* __restrict__ Qb,
                                                 const unsigned short* __restrict__ Kb,
                                                 const unsigned short* __restrict__ Vt,
                                                 unsigned short* __restrict__ ob) {
    __shared__ short Ks[2][64 * 64];
    __shared__ short Vs[2][64 * 64];
    __shared__ short Pl[4][16 * 72];
    int tid = threadIdx.x;
    int lane = tid & 63, wave = tid >> 6;
    int ln16 = lane & 15, q = lane >> 4;
    int b = blockIdx.z, h = blockIdx.y, q0 = blockIdx.x * 64;
    int sw = ln16 & 7;                       // read-side chunk swizzle (row&7 == ln16&7)
    int rc0 = (q ^ sw) * 8;                  // chunk offsets for the two K-halves
    int rc1 = ((4 + q) ^ sw) * 8;

    const unsigned short* qrow = Qb + ((size_t)(b * 1024 + q0 + wave * 16 + ln16)) * 1024 + h * 64;
    bf16x8 qf0 = *(const bf16x8*)(qrow + q * 8);
    bf16x8 qf1 = *(const bf16x8*)(qrow + 32 + q * 8);

    floatx4 o[4];
    #pragma unroll
    for (int td = 0; td < 4; td++) o[td] = (floatx4){0.f, 0.f, 0.f, 0.f};
    float mrow[4] = {-1e30f, -1e30f, -1e30f, -1e30f};
    float lrow[4] = {0.f, 0.f, 0.f, 0.f};

    const unsigned short* kbase0 = Kb + ((size_t)(b * 1024)) * 1024 + h * 64;
    const unsigned short* vbase0 = Vt + ((size_t)((b * 16 + h) * 64)) * 1024;

    // stage one 64-row K/V chunk into buffer `bi` (4 loads/thread, src pre-swizzled)
    auto stage = [&](int bi, int l0) {
        #pragma unroll
        for (int it = 0; it < 2; it++) {
            int j = tid + it * 256;
            int row = j >> 3, g = j & 7, gc = g ^ (row & 7);
            load_lds16(kbase0 + (size_t)(l0 + row) * 1024 + gc * 8, &Ks[bi][j * 8]);
            load_lds16(vbase0 + (size_t)row * 1024 + l0 + gc * 8, &Vs[bi][j * 8]);
        }
    };

    stage(0, 0);
    for (int ch = 0; ch < 16; ch++) {
        int cur = ch & 1;
        // WAR: all waves finished reading buf[cur^1] (prev iteration's compute)
        __builtin_amdgcn_s_barrier();
        if (ch < 15) {
            stage(cur ^ 1, (ch + 1) * 64);
            asm volatile("s_waitcnt vmcnt(4)" ::: "memory");   // cur loads done; next in flight
        } else {
            asm volatile("s_waitcnt vmcnt(0)" ::: "memory");
        }
        __builtin_amdgcn_s_barrier();        // cur buffer visible to all waves
        __builtin_amdgcn_sched_barrier(0);

        floatx4 s[4];
        #pragma unroll
        for (int t = 0; t < 4; t++) {
            s[t] = (floatx4){0.f, 0.f, 0.f, 0.f};
            int kr = (t * 16 + ln16) * 64;
            bf16x8 kf0 = *(const bf16x8*)&Ks[cur][kr + rc0];
            bf16x8 kf1 = *(const bf16x8*)&Ks[cur][kr + rc1];
            s[t] = __builtin_amdgcn_mfma_f32_16x16x32_bf16(qf0, kf0, s[t], 0, 0, 0);
            s[t] = __builtin_amdgcn_mfma_f32_16x16x32_bf16(qf1, kf1, s[t], 0, 0, 0);
        }
        float cm[4], rs[4], p[4][4];
        #pragma unroll
        for (int r = 0; r < 4; r++)
            cm[r] = fmaxf(fmaxf(s[0][r], s[1][r]), fmaxf(s[2][r], s[3][r]));
        #pragma unroll
        for (int off = 1; off < 16; off <<= 1) {
            #pragma unroll
            for (int r = 0; r < 4; r++) cm[r] = fmaxf(cm[r], __shfl_xor(cm[r], off));
        }
        #pragma unroll
        for (int r = 0; r < 4; r++) {
            float mnew = fmaxf(mrow[r], cm[r]);
            float alpha = __expf(mrow[r] - mnew);
            mrow[r] = mnew;
            rs[r] = 0.f;
            #pragma unroll
            for (int t = 0; t < 4; t++) {
                p[t][r] = __expf(s[t][r] - mnew);
                rs[r] += p[t][r];
            }
            lrow[r] *= alpha;
            #pragma unroll
            for (int td = 0; td < 4; td++) o[td][r] *= alpha;
        }
        #pragma unroll
        for (int off = 1; off < 16; off <<= 1) {
            #pragma unroll
            for (int r = 0; r < 4; r++) rs[r] += __shfl_xor(rs[r], off);
        }
        #pragma unroll
        for (int r = 0; r < 4; r++) lrow[r] += rs[r];

        // Pl[wave] is written and read by the SAME wave only: no barrier needed.
        short* pw = &Pl[wave][0];
        #pragma unroll
        for (int t = 0; t < 4; t++)
            #pragma unroll
            for (int r = 0; r < 4; r++)
                pw[(q * 4 + r) * 72 + t * 16 + ln16] = (short)f2bf(p[t][r]);
        bf16x8 pf0 = *(const bf16x8*)&pw[ln16 * 72 + q * 8];
        bf16x8 pf1 = *(const bf16x8*)&pw[ln16 * 72 + 32 + q * 8];
        #pragma unroll
        for (int td = 0; td < 4; td++) {
            int vr = (td * 16 + ln16) * 64;
            bf16x8 vf0 = *(const bf16x8*)&Vs[cur][vr + rc0];
            bf16x8 vf1 = *(const bf16x8*)&Vs[cur][vr + rc1];
            o[td] = __builtin_amdgcn_mfma_f32_16x16x32_bf16(pf0, vf0, o[td], 0, 0, 0);
            o[td] = __builtin_amdgcn_mfma_f32_16x16x32_bf16(pf1, vf1, o[td], 0, 0, 0);
        }
    }
    #pragma unroll
    for (int td = 0; td < 4; td++) {
        #pragma unroll
        for (int r = 0; r < 4; r++) {
            int row = q0 + wave * 16 + q * 4 + r;
            int col = h * 64 + td * 16 + ln16;
            ob[((size_t)(b * 1024 + row)) * 1024 + col] = f2bf(o[td][r] / lrow[r]);
        }
    }
}

// ------- batched weight transpose + bf16: in fp32 [z][K][N] -> out bf16 [z][N][K] ----
__global__ __launch_bounds__(256) void wtrans_kernel(const float* __restrict__ in,
                                                     unsigned short* __restrict__ out,
                                                     int K, int N) {
    __shared__ float t[64][65];
    int n0 = blockIdx.x * 64, k0 = blockIdx.y * 64, z = blockIdx.z;
    in  += (size_t)z * K * N;
    out += (size_t)z * N * K;
    for (int i = threadIdx.x; i < 4096; i += 256) {
        int kr = i >> 6, nc = i & 63;
        t[kr][nc] = in[(size_t)(k0 + kr) * N + n0 + nc];
    }
    __syncthreads();
    for (int i = threadIdx.x; i < 4096; i += 256) {
        int nr = i >> 6, kc = i & 63;
        out[(size_t)(n0 + nr) * K + k0 + kc] = f2bf(t[kc][nr]);
    }
}

// ------- bf16 MFMA GEMM, BK=64, XOR-swizzled LDS -------------------------------
// C = act(A@B + bias)[+C]; A[M][lda] bf16, Bt[N][lda] bf16.
// SPLITK: blockIdx.z selects K-chunk of size K; raw partials to Cf + z*M*N.
template <int BM, int BN, int WM, int WN, int ACT, bool ADDC, bool OUTBF16, bool SPLITK>
__global__ __launch_bounds__(256) void gemm_bf16(const unsigned short* __restrict__ A,
                                                 const unsigned short* __restrict__ Bt,
                                                 const float* __restrict__ bias,
                                                 float* __restrict__ Cf,
                                                 unsigned short* __restrict__ Cb,
                                                 int M, int N, int K, int lda) {
    constexpr int MT = BM / (WM * 16);
    constexpr int NT = BN / (WN * 16);
    __shared__ short As[BM * 64];
    __shared__ short Bs[BN * 64];
    int tid = threadIdx.x;
    int lane = tid & 63, wave = tid >> 6;
    int wm = wave / WN, wn = wave % WN;
    int ln16 = lane & 15, q = lane >> 4;
    int m0 = blockIdx.y * BM, n0 = blockIdx.x * BN;
    int kOff = SPLITK ? blockIdx.z * K : 0;

    floatx4 acc[MT][NT];
    #pragma unroll
    for (int i = 0; i < MT; i++)
        #pragma unroll
        for (int j = 0; j < NT; j++) acc[i][j] = (floatx4){0.f, 0.f, 0.f, 0.f};

    int kSteps = K >> 6;
    for (int ks = 0; ks < kSteps; ks++) {
        int k0 = kOff + (ks << 6);
        #pragma unroll
        for (int it = 0; it < BM / 32; it++) {
            int i = tid + it * 256;
            int row = i >> 3, gc = (i & 7) ^ (row & 7);   // XOR chunk swizzle
            load_lds16(A + (size_t)(m0 + row) * lda + k0 + gc * 8, &As[i * 8]);
        }
        #pragma unroll
        for (int it = 0; it < BN / 32; it++) {
            int i = tid + it * 256;
            int row = i >> 3, gc = (i & 7) ^ (row & 7);
            load_lds16(Bt + (size_t)(n0 + row) * lda + k0 + gc * 8, &Bs[i * 8]);
        }
        __syncthreads();
        bf16x8 af[2][MT], bf[2][NT];
        #pragma unroll
        for (int h = 0; h < 2; h++) {
            #pragma unroll
            for (int mi = 0; mi < MT; mi++) {
                int row = wm * (BM / WM) + mi * 16 + ln16;
                af[h][mi] = *(const bf16x8*)&As[row * 64 + (((h * 4 + q) ^ (row & 7)) * 8)];
            }
            #pragma unroll
            for (int ni = 0; ni < NT; ni++) {
                int row = wn * (BN / WN) + ni * 16 + ln16;
                bf[h][ni] = *(const bf16x8*)&Bs[row * 64 + (((h * 4 + q) ^ (row & 7)) * 8)];
            }
        }
        #pragma unroll
        for (int h = 0; h < 2; h++)
            #pragma unroll
            for (int mi = 0; mi < MT; mi++)
                #pragma unroll
                for (int ni = 0; ni < NT; ni++)
                    acc[mi][ni] = __builtin_amdgcn_mfma_f32_16x16x32_bf16(af[h][mi], bf[h][ni], acc[mi][ni], 0, 0, 0);
        __syncthreads();
    }

    int q4 = q * 4;
    float* Cp = SPLITK ? (Cf + (size_t)blockIdx.z * M * N) : Cf;
    #pragma unroll
    for (int ni = 0; ni < NT; ni++) {
        int col = n0 + wn * (BN / WN) + ni * 16 + ln16;
        float bv = SPLITK ? 0.f : bias[col];
        #pragma unroll
        for (int mi = 0; mi < MT; mi++) {
            #pragma unroll
            for (int r = 0; r < 4; r++) {
                int row = m0 + wm * (BM / WM) + mi * 16 + q4 + r;
                size_t off = (size_t)row * N + col;
                float v = acc[mi][ni][r] + bv;
                if (!SPLITK && ACT == 1) v = 0.5f * v * (1.f + erff(v * 0.70710678118654752f));
                if (!SPLITK && ADDC) v += Cf[off];
                if (!SPLITK && OUTBF16) Cb[off] = f2bf(v);
                else Cp[off] = v;
            }
        }
    }
}

// ------- fused split-K reduce + layernorm: x = xb + P0 + P1 + bias -> xb, LN(x) -> Y ----
__global__ __launch_bounds__(256) void skln_kernel(const float* __restrict__ P,
                                                   const float* __restrict__ bias,
                                                   float* __restrict__ xb,
                                                   unsigned short* __restrict__ Y,
                                                   const float* __restrict__ g,
                                                   const float* __restrict__ b,
                                                   float eps, int affine) {
    int row = blockIdx.x;                        // 2048 rows
    int t = threadIdx.x;
    int idx = row * 256 + t;                     // float4 index
    float4 a = ((const float4*)P)[idx];
    float4 c = ((const float4*)P)[idx + 524288];
    float4 x = ((float4*)xb)[idx];
    const float4 bb = *(const float4*)(bias + t * 4);
    x.x += a.x + c.x + bb.x;
    x.y += a.y + c.y + bb.y;
    x.z += a.z + c.z + bb.z;
    x.w += a.w + c.w + bb.w;
    ((float4*)xb)[idx] = x;
    float s = x.x + x.y + x.z + x.w;
    float sq = x.x * x.x + x.y * x.y + x.z * x.z + x.w * x.w;
    __shared__ float red[8];
    #pragma unroll
    for (int off = 32; off; off >>= 1) { s += __shfl_xor(s, off); sq += __shfl_xor(sq, off); }
    int wid = t >> 6, lane = t & 63;
    if (!lane) { red[wid] = s; red[wid + 4] = sq; }
    __syncthreads();
    s = red[0] + red[1] + red[2] + red[3];
    sq = red[4] + red[5] + red[6] + red[7];
    float mu = s * (1.f / 1024.f);
    float var = sq * (1.f / 1024.f) - mu * mu;
    float rs = rsqrtf(var + eps);
    int cidx = t * 4;
    float4 y;
    if (affine) {
        y.x = (x.x - mu) * rs * g[cidx + 0] + b[cidx + 0];
        y.y = (x.y - mu) * rs * g[cidx + 1] + b[cidx + 1];
        y.z = (x.z - mu) * rs * g[cidx + 2] + b[cidx + 2];
        y.w = (x.w - mu) * rs * g[cidx + 3] + b[cidx + 3];
    } else {
        y.x = (x.x - mu) * rs; y.y = (x.y - mu) * rs;
        y.z = (x.z - mu) * rs; y.w = (x.w - mu) * rs;
    }
    ushort4 o;
    o.x = f2bf(y.x); o.y = f2bf(y.y); o.z = f2bf(y.z); o.w = f2bf(y.w);
    *(ushort4*)(Y + (size_t)row * 1024 + cidx) = o;
}

// ---------------- unpatchify ----------------
__global__ void unpatchify_kernel(const float* __restrict__ xf, float* __restrict__ img) {
    int idx = blockIdx.x * 256 + threadIdx.x;
    int x = idx & 63, y = (idx >> 6) & 63, ch = (idx >> 12) & 63, b = idx >> 18;
    int hh = y >> 1, ww = x >> 1, p = y & 1, qq = x & 1;
    img[idx] = xf[((size_t)b * 1024 + hh * 32 + ww) * 256 + ch * 4 + p * 2 + qq];
}

// ------- conv1: 64->16, 3x3, pad1, relu -------
__global__ __launch_bounds__(256) void conv1_kernel(const float* __restrict__ img,
                                                    const float* __restrict__ w,
                                                    const float* __restrict__ bias,
                                                    float* __restrict__ out) {
    __shared__ float Ls[64 * 3 * 66];
    __shared__ float Ws[16 * 580];
    int tid = threadIdx.x;
    int y = blockIdx.x, b = blockIdx.y;
    for (int i = tid; i < 9216; i += 256) {
        int oc = i / 576, rem = i % 576;
        Ws[oc * 580 + rem] = w[i];
    }
    for (int i = tid; i < 12288; i += 256) {
        int r = i >> 6, x = i & 63;
        int ic = r / 3, ky = r % 3;
        int yy = y + ky - 1;
        float v = (yy >= 0 && yy < 64) ? img[((size_t)(b * 64 + ic) * 64 + yy) * 64 + x] : 0.f;
        Ls[(ic * 3 + ky) * 66 + x + 1] = v;
        if (x == 0)  Ls[(ic * 3 + ky) * 66 + 0]  = 0.f;
        if (x == 63) Ls[(ic * 3 + ky) * 66 + 65] = 0.f;
    }
    __syncthreads();
    int oc = tid >> 4, xg = (tid & 15) * 4;
    float bv = bias[oc];
    float acc0 = bv, acc1 = bv, acc2 = bv, acc3 = bv;
    for (int ic = 0; ic < 64; ic++) {
        const float* wr = &Ws[oc * 580 + ic * 9];
        float w00 = wr[0], w01 = wr[1], w02 = wr[2];
        float w10 = wr[3], w11 = wr[4], w12 = wr[5];
        float w20 = wr[6], w21 = wr[7], w22 = wr[8];
        const float* l0 = &Ls[(ic * 3 + 0) * 66 + xg];
        const float* l1 = &Ls[(ic * 3 + 1) * 66 + xg];
        const float* l2 = &Ls[(ic * 3 + 2) * 66 + xg];
        float a0 = l0[0], a1 = l0[1], a2 = l0[2], a3 = l0[3], a4 = l0[4], a5 = l0[5];
        float b0 = l1[0], b1 = l1[1], b2 = l1[2], b3 = l1[3], b4 = l1[4], b5 = l1[5];
        float c0 = l2[0], c1 = l2[1], c2 = l2[2], c3 = l2[3], c4 = l2[4], c5 = l2[5];
        acc0 += a0*w00 + a1*w01 + a2*w02 + b0*w10 + b1*w11 + b2*w12 + c0*w20 + c1*w21 + c2*w22;
        acc1 += a1*w00 + a2*w01 + a3*w02 + b1*w10 + b2*w11 + b3*w12 + c1*w20 + c2*w21 + c3*w22;
        acc2 += a2*w00 + a3*w01 + a4*w02 + b2*w10 + b3*w11 + b4*w12 + c2*w20 + c3*w21 + c4*w22;
        acc3 += a3*w00 + a4*w01 + a5*w02 + b3*w10 + b4*w11 + b5*w12 + c3*w20 + c4*w21 + c5*w22;
    }
    float* op = out + (((size_t)(b * 16 + oc) * 64 + y) * 64 + xg);
    op[0] = fmaxf(acc0, 0.f);
    op[1] = fmaxf(acc1, 0.f);
    op[2] = fmaxf(acc2, 0.f);
    op[3] = fmaxf(acc3, 0.f);
}

// ------- conv2: 16->3, 3x3, pad1 -------
__global__ __launch_bounds__(256) void conv2_kernel(const float* __restrict__ in,
                                                    const float* __restrict__ w,
                                                    const float* __restrict__ bias,
                                                    float* __restrict__ out) {
    __shared__ float Ls[16 * 3 * 66];
    __shared__ float Ws[3 * 160];
    int tid = threadIdx.x;
    int y = blockIdx.x, b = blockIdx.y;
    for (int i = tid; i < 432; i += 256) {
        int oc = i / 144, rem = i % 144;
        Ws[oc * 160 + rem] = w[i];
    }
    for (int i = tid; i < 3072; i += 256) {
        int r = i >> 6, x = i & 63;
        int ic = r / 3, ky = r % 3;
        int yy = y + ky - 1;
        float v = (yy >= 0 && yy < 64) ? in[((size_t)(b * 16 + ic) * 64 + yy) * 64 + x] : 0.f;
        Ls[(ic * 3 + ky) * 66 + x + 1] = v;
        if (x == 0)  Ls[(ic * 3 + ky) * 66 + 0]  = 0.f;
        if (x == 63) Ls[(ic * 3 + ky) * 66 + 65] = 0.f;
    }
    __syncthreads();
    int oc = tid >> 6, x = tid & 63;
    if (oc < 3) {
        float acc = bias[oc];
        for (int ic = 0; ic < 16; ic++) {
            const float* wr = &Ws[oc * 160 + ic * 9];
            const float* l0 = &Ls[(ic * 3 + 0) * 66 + x];
            const float* l1 = &Ls[(ic * 3 + 1) * 66 + x];
            const float* l2 = &Ls[(ic * 3 + 2) * 66 + x];
            acc += l0[0]*wr[0] + l0[1]*wr[1] + l0[2]*wr[2]
                 + l1[0]*wr[3] + l1[1]*wr[4] + l1[2]*wr[5]
                 + l2[0]*wr[6] + l2[1]*wr[7] + l2[2]*wr[8];
        }
        out[((size_t)(b * 3 + oc) * 64 + y) * 64 + x] = acc;
    }
}

// ---------------- launch ----------------
extern "C" void kernel_launch(void* const* d_in, const int* in_sizes, int n_in,
                              void* d_out, int out_size, void* d_ws, size_t ws_size,
                              hipStream_t stream) {
    const float* x_in   = (const float*)d_in[0];
    const float* qkv_w  = (const float*)d_in[1];
    const float* qkv_b  = (const float*)d_in[2];
    const float* proj_w = (const float*)d_in[3];
    const float* proj_b = (const float*)d_in[4];
    const float* nq_g   = (const float*)d_in[5];
    const float* nq_b   = (const float*)d_in[6];
    const float* nk_g   = (const float*)d_in[7];
    const float* nk_b   = (const float*)d_in[8];
    const float* n1_g   = (const float*)d_in[9];
    const float* n1_b   = (const float*)d_in[10];
    const float* n2_g   = (const float*)d_in[11];
    const float* n2_b   = (const float*)d_in[12];
    const float* fc1_w  = (const float*)d_in[13];
    const float* fc1_b  = (const float*)d_in[14];
    const float* fc2_w  = (const float*)d_in[15];
    const float* fc2_b  = (const float*)d_in[16];
    const float* fin_w  = (const float*)d_in[17];
    const float* fin_b  = (const float*)d_in[18];
    const float* c1_w   = (const float*)d_in[19];
    const float* c1_b   = (const float*)d_in[20];
    const float* c2_w   = (const float*)d_in[21];
    const float* c2_b   = (const float*)d_in[22];
    float* out = (float*)d_out;

    char* w = (char*)d_ws;
    float* xb           = (float*)w;          w += (size_t)2 * 1024 * 1024 * 4;
    unsigned short* hnb = (unsigned short*)w; w += (size_t)2 * 1024 * 1024 * 2;
    float* qkv          = (float*)w;          w += (size_t)2 * 1024 * 3072 * 4;
    unsigned short* obb = (unsigned short*)w; w += (size_t)2 * 1024 * 1024 * 2;
    unsigned short* mhb = (unsigned short*)w; w += (size_t)2 * 1024 * 4096 * 2;
    float* xf           = (float*)w;          w += (size_t)2 * 1024 * 256 * 4;
    float* img          = (float*)w;          w += (size_t)2 * 64 * 64 * 64 * 4;
    float* c1o          = (float*)w;          w += (size_t)2 * 16 * 64 * 64 * 4;
    unsigned short* Qb  = (unsigned short*)w; w += (size_t)2 * 1024 * 1024 * 2;
    unsigned short* Kb  = (unsigned short*)w; w += (size_t)2 * 1024 * 1024 * 2;
    unsigned short* Vt  = (unsigned short*)w; w += (size_t)2 * 16 * 64 * 1024 * 2;
    float* skb          = (float*)w;          w += (size_t)2 * 2048 * 1024 * 4;   // split-K partials
    unsigned short* WQ  = (unsigned short*)w; w += (size_t)4 * 1024 * 3072 * 2;
    unsigned short* WP  = (unsigned short*)w; w += (size_t)4 * 1024 * 1024 * 2;
    unsigned short* W1  = (unsigned short*)w; w += (size_t)4 * 1024 * 4096 * 2;
    unsigned short* W2  = (unsigned short*)w; w += (size_t)4 * 4096 * 1024 * 2;
    unsigned short* WF  = (unsigned short*)w; w += (size_t)1024 * 256 * 2;

    wtrans_kernel<<<dim3(48, 16, 4), 256, 0, stream>>>(qkv_w, WQ, 1024, 3072);
    wtrans_kernel<<<dim3(16, 16, 4), 256, 0, stream>>>(proj_w, WP, 1024, 1024);
    wtrans_kernel<<<dim3(64, 16, 4), 256, 0, stream>>>(fc1_w, W1, 1024, 4096);
    wtrans_kernel<<<dim3(16, 64, 4), 256, 0, stream>>>(fc2_w, W2, 4096, 1024);
    wtrans_kernel<<<dim3(4, 16, 1), 256, 0, stream>>>(fin_w, WF, 1024, 256);

    posembed_kernel<<<8192, 256, 0, stream>>>(x_in, xb);

    for (int i = 0; i < 4; i++) {
        if (i == 0)
            ln_kernel<<<2048, 256, 0, stream>>>(xb, hnb, n1_g, n1_b, 1e-5f, 1);
        gemm_bf16<64, 128, 2, 2, 0, false, false, false><<<dim3(24, 32), 256, 0, stream>>>(
            hnb, WQ + (size_t)i * 3072 * 1024, qkv_b + i * 3072, qkv, nullptr, 2048, 3072, 1024, 1024);
        qkvprep_kernel<<<dim3(16, 16, 2), 256, 0, stream>>>(
            qkv, nq_g + i * 64, nq_b + i * 64, nk_g + i * 64, nk_b + i * 64, Qb, Kb, Vt);
        attn_mfma<<<dim3(16, 16, 2), 256, 0, stream>>>(Qb, Kb, Vt, obb);
        gemm_bf16<64, 64, 2, 2, 0, true, false, false><<<dim3(16, 32), 256, 0, stream>>>(
            obb, WP + (size_t)i * 1024 * 1024, proj_b + i * 1024, xb, nullptr, 2048, 1024, 1024, 1024);
        ln_kernel<<<2048, 256, 0, stream>>>(xb, hnb, n2_g + i * 1024, n2_b + i * 1024, 1e-5f, 1);
        gemm_bf16<64, 128, 2, 2, 1, false, true, false><<<dim3(32, 32), 256, 0, stream>>>(
            hnb, W1 + (size_t)i * 4096 * 1024, fc1_b + i * 4096, nullptr, mhb, 2048, 4096, 1024, 1024);
        gemm_bf16<64, 64, 2, 2, 0, false, false, true><<<dim3(16, 32, 2), 256, 0, stream>>>(
            mhb, W2 + (size_t)i * 1024 * 4096, fc2_b + i * 1024, skb, nullptr, 2048, 1024, 2048, 4096);
        // fused: xb += P0+P1+bias; hnb = LN(xb) (next block's ln1, or the final eps=1e-6 LN)
        if (i < 3)
            skln_kernel<<<2048, 256, 0, stream>>>(skb, fc2_b + i * 1024, xb, hnb,
                                                  n1_g + (i + 1) * 1024, n1_b + (i + 1) * 1024, 1e-5f, 1);
        else
            skln_kernel<<<2048, 256, 0, stream>>>(skb, fc2_b + i * 1024, xb, hnb,
                                                  nullptr, nullptr, 1e-6f, 0);
    }

    gemm_bf16<64, 64, 2, 2, 0, false, false, false><<<dim3(4, 32), 256, 0, stream>>>(
        hnb, WF, fin_b, xf, nullptr, 2048, 256, 1024, 1024);
    unpatchify_kernel<<<2048, 256, 0, stream>>>(xf, img);
    conv1_kernel<<<dim3(64, 2), 256, 0, stream>>>(img, c1_w, c1_b, c1o);
    conv2_kernel<<<dim3(64, 2), 256, 0, stream>>>(c1o, c2_w, c2_b, out);
}

// Round 8
// 940.126 us; speedup vs baseline: 1.2981x; 1.0272x over previous
//
#include <hip/hip_runtime.h>
#include <hip/hip_bf16.h>
#include <math.h>

typedef float floatx4 __attribute__((ext_vector_type(4)));
typedef short bf16x8 __attribute__((ext_vector_type(8)));   // 8 bf16 in 4 VGPRs

__device__ __forceinline__ unsigned short f2bf(float x) {
    union { float f; unsigned int u; } v; v.f = x;
    unsigned int r = v.u + 0x7fffu + ((v.u >> 16) & 1u);    // RNE
    return (unsigned short)(r >> 16);
}

__device__ __forceinline__ void load_lds16(const void* g, void* l) {
    __builtin_amdgcn_global_load_lds(
        (const __attribute__((address_space(1))) unsigned int*)(uintptr_t)g,
        (__attribute__((address_space(3))) unsigned int*)(uintptr_t)l, 16, 0, 0);
}

// ---------------- pos embed + input add (float math: |err| ~1e-6 << bf16 noise) ----
__global__ void posembed_kernel(const float* __restrict__ xin, float* __restrict__ xb) {
    int idx = blockIdx.x * 256 + threadIdx.x;     // 2*1024*1024
    int c = idx & 1023;
    int n = (idx >> 10) & 1023;
    int pos = (c < 512) ? (n & 31) : (n >> 5);
    int cc = c & 511;
    int k = cc & 255;
    float om = expf(-(float)k * (9.210340371976184f / 256.0f));
    float arg = (float)pos * om;
    float e = (cc < 256) ? sinf(arg) : cosf(arg);
    xb[idx] = xin[idx] + e;
}

// ---------------- layernorm over C=1024, bf16 output ----------------
__global__ __launch_bounds__(256) void ln_kernel(const float* __restrict__ X,
                                                 unsigned short* __restrict__ Y,
                                                 const float* __restrict__ g,
                                                 const float* __restrict__ b,
                                                 float eps, int affine) {
    int row = blockIdx.x;
    const float4* xr = (const float4*)(X + (size_t)row * 1024);
    float4 x = xr[threadIdx.x];
    float s = x.x + x.y + x.z + x.w;
    float sq = x.x * x.x + x.y * x.y + x.z * x.z + x.w * x.w;
    __shared__ float red[8];
    #pragma unroll
    for (int off = 32; off; off >>= 1) { s += __shfl_xor(s, off); sq += __shfl_xor(sq, off); }
    int wid = threadIdx.x >> 6, lane = threadIdx.x & 63;
    if (!lane) { red[wid] = s; red[wid + 4] = sq; }
    __syncthreads();
    s = red[0] + red[1] + red[2] + red[3];
    sq = red[4] + red[5] + red[6] + red[7];
    float mu = s * (1.f / 1024.f);
    float var = sq * (1.f / 1024.f) - mu * mu;
    float rs = rsqrtf(var + eps);
    int c = threadIdx.x * 4;
    float4 y;
    if (affine) {
        y.x = (x.x - mu) * rs * g[c + 0] + b[c + 0];
        y.y = (x.y - mu) * rs * g[c + 1] + b[c + 1];
        y.z = (x.z - mu) * rs * g[c + 2] + b[c + 2];
        y.w = (x.w - mu) * rs * g[c + 3] + b[c + 3];
    } else {
        y.x = (x.x - mu) * rs; y.y = (x.y - mu) * rs;
        y.z = (x.z - mu) * rs; y.w = (x.w - mu) * rs;
    }
    ushort4 o;
    o.x = f2bf(y.x); o.y = f2bf(y.y); o.z = f2bf(y.z); o.w = f2bf(y.w);
    *(ushort4*)(Y + (size_t)row * 1024 + c) = o;
}

// ---- merged qk-norm + V transpose: one pass over qkv ----
__global__ __launch_bounds__(256) void qkvprep_kernel(const float* __restrict__ qkv,
                                                      const float* __restrict__ nqg,
                                                      const float* __restrict__ nqb,
                                                      const float* __restrict__ nkg,
                                                      const float* __restrict__ nkb,
                                                      unsigned short* __restrict__ Qb,
                                                      unsigned short* __restrict__ Kb,
                                                      unsigned short* __restrict__ Vt) {
    __shared__ float t[64][65];
    int tid = threadIdx.x;
    int l0 = blockIdx.x * 64, h = blockIdx.y, b = blockIdx.z;
    for (int i = tid; i < 4096; i += 256) {
        int lr = i >> 6, dd = i & 63;
        t[lr][dd] = qkv[((size_t)(b * 1024 + l0 + lr)) * 3072 + 2048 + h * 64 + dd];
    }
    __syncthreads();
    for (int i = tid; i < 4096; i += 256) {
        int dd = i >> 6, lc = i & 63;
        Vt[((size_t)((b * 16 + h) * 64 + dd)) * 1024 + l0 + lc] = f2bf(t[lc][dd]);
    }
    int wave = tid >> 6, lane = tid & 63;
    float gq = nqg[lane], bq = nqb[lane], gk = nkg[lane], bk = nkb[lane];
    for (int i = 0; i < 16; i++) {
        int l = l0 + wave + 4 * i;
        const float* base = qkv + (size_t)(b * 1024 + l) * 3072 + h * 64 + lane;
        #pragma unroll
        for (int part = 0; part < 2; part++) {
            float v = base[part * 1024];
            float s = v, sq = v * v;
            #pragma unroll
            for (int off = 32; off; off >>= 1) { s += __shfl_xor(s, off); sq += __shfl_xor(sq, off); }
            float mu = s * (1.f / 64.f);
            float var = sq * (1.f / 64.f) - mu * mu;
            float rs = rsqrtf(var + 1e-5f);
            float y = (v - mu) * rs * (part ? gk : gq) + (part ? bk : bq);
            unsigned short* dst = part ? Kb : Qb;
            dst[(size_t)(b * 1024 + l) * 1024 + h * 64 + lane] = f2bf(y * (part ? 1.f : 0.125f));
        }
    }
}

// ---- MFMA flash attention: block = (64 q-rows, head, b); 4 waves x 16 rows ----
// R7-verified shell (XOR-swizzled staging + counted-vmcnt double buffer) with
// SWAPPED QK^T: s[t] = mfma(K,Q) so each lane owns ONE Q-row (ln16) and 16
// K-positions (16t+4q+r). A/B operand per-lane layouts of 16x16x32 are
// identical, so the same fragments feed the swapped mfma. Softmax reductions
// become 15 local ops + 2 shfl_xor (was 16 shuffles each for max and sum);
// alpha/lrow are scalars broadcast by 4 __shfl for the O-rescale.
__global__ __launch_bounds__(256) void attn_mfma(const unsigned short* __restrict__ Qb,
                                                 const unsigned short* __restrict__ Kb,
                                                 const unsigned short* __restrict__ Vt,
                                                 unsigned short* __restrict__ ob) {
    __shared__ short Ks[2][64 * 64];
    __shared__ short Vs[2][64 * 64];
    __shared__ short Pl[4][16 * 72];
    int tid = threadIdx.x;
    int lane = tid & 63, wave = tid >> 6;
    int ln16 = lane & 15, q = lane >> 4;
    int q4 = q * 4;
    int b = blockIdx.z, h = blockIdx.y, q0 = blockIdx.x * 64;
    int sw = ln16 & 7;                       // read-side chunk swizzle (row&7 == ln16&7)
    int rc0 = (q ^ sw) * 8;                  // chunk offsets for the two halves
    int rc1 = ((4 + q) ^ sw) * 8;

    const unsigned short* qrow = Qb + ((size_t)(b * 1024 + q0 + wave * 16 + ln16)) * 1024 + h * 64;
    bf16x8 qf0 = *(const bf16x8*)(qrow + q * 8);
    bf16x8 qf1 = *(const bf16x8*)(qrow + 32 + q * 8);

    floatx4 o[4];
    #pragma unroll
    for (int td = 0; td < 4; td++) o[td] = (floatx4){0.f, 0.f, 0.f, 0.f};
    float mrow = -1e30f;                     // running max for Q row ln16
    float lrow = 0.f;                        // running denom for Q row ln16

    const unsigned short* kbase0 = Kb + ((size_t)(b * 1024)) * 1024 + h * 64;
    const unsigned short* vbase0 = Vt + ((size_t)((b * 16 + h) * 64)) * 1024;

    // stage one 64-row K/V chunk into buffer `bi` (4 loads/thread, src pre-swizzled)
    auto stage = [&](int bi, int l0) {
        #pragma unroll
        for (int it = 0; it < 2; it++) {
            int j = tid + it * 256;
            int row = j >> 3, g = j & 7, gc = g ^ (row & 7);
            load_lds16(kbase0 + (size_t)(l0 + row) * 1024 + gc * 8, &Ks[bi][j * 8]);
            load_lds16(vbase0 + (size_t)row * 1024 + l0 + gc * 8, &Vs[bi][j * 8]);
        }
    };

    stage(0, 0);
    for (int ch = 0; ch < 16; ch++) {
        int cur = ch & 1;
        // WAR: all waves finished reading buf[cur^1] (prev iteration's compute)
        __builtin_amdgcn_s_barrier();
        if (ch < 15) {
            stage(cur ^ 1, (ch + 1) * 64);
            asm volatile("s_waitcnt vmcnt(4)" ::: "memory");   // cur loads done; next in flight
        } else {
            asm volatile("s_waitcnt vmcnt(0)" ::: "memory");
        }
        __builtin_amdgcn_s_barrier();        // cur buffer visible to all waves
        __builtin_amdgcn_sched_barrier(0);

        // swapped QK^T: s[t][r] = S[Kpos = 16t+4q+r][Qrow = ln16]
        floatx4 s[4];
        #pragma unroll
        for (int t = 0; t < 4; t++) {
            s[t] = (floatx4){0.f, 0.f, 0.f, 0.f};
            int kr = (t * 16 + ln16) * 64;
            bf16x8 kf0 = *(const bf16x8*)&Ks[cur][kr + rc0];
            bf16x8 kf1 = *(const bf16x8*)&Ks[cur][kr + rc1];
            s[t] = __builtin_amdgcn_mfma_f32_16x16x32_bf16(kf0, qf0, s[t], 0, 0, 0);
            s[t] = __builtin_amdgcn_mfma_f32_16x16x32_bf16(kf1, qf1, s[t], 0, 0, 0);
        }
        // lane-local softmax over the 16 held K-positions + 2-round cross-group reduce
        float pmax = s[0][0];
        #pragma unroll
        for (int t = 0; t < 4; t++)
            #pragma unroll
            for (int r = 0; r < 4; r++) pmax = fmaxf(pmax, s[t][r]);
        pmax = fmaxf(pmax, __shfl_xor(pmax, 16));
        pmax = fmaxf(pmax, __shfl_xor(pmax, 32));
        float mnew = fmaxf(mrow, pmax);
        float alpha = __expf(mrow - mnew);
        mrow = mnew;
        float p[4][4];
        float psum = 0.f;
        #pragma unroll
        for (int t = 0; t < 4; t++)
            #pragma unroll
            for (int r = 0; r < 4; r++) {
                p[t][r] = __expf(s[t][r] - mnew);
                psum += p[t][r];
            }
        psum += __shfl_xor(psum, 16);
        psum += __shfl_xor(psum, 32);
        lrow = lrow * alpha + psum;
        // O-rescale: o[td][r] belongs to Q row q4+r -> broadcast that row's alpha
        float af[4];
        #pragma unroll
        for (int r = 0; r < 4; r++) af[r] = __shfl(alpha, q4 + r);
        #pragma unroll
        for (int td = 0; td < 4; td++)
            #pragma unroll
            for (int r = 0; r < 4; r++) o[td][r] *= af[r];

        // P store: row ln16, Kpos 16t+4q+r. Read side (A-fragment) unchanged.
        // Pl[wave] is written and read by the SAME wave only: no barrier needed.
        short* pw = &Pl[wave][0];
        #pragma unroll
        for (int t = 0; t < 4; t++)
            #pragma unroll
            for (int r = 0; r < 4; r++)
                pw[ln16 * 72 + t * 16 + q4 + r] = (short)f2bf(p[t][r]);
        bf16x8 pf0 = *(const bf16x8*)&pw[ln16 * 72 + q * 8];
        bf16x8 pf1 = *(const bf16x8*)&pw[ln16 * 72 + 32 + q * 8];
        #pragma unroll
        for (int td = 0; td < 4; td++) {
            int vr = (td * 16 + ln16) * 64;
            bf16x8 vf0 = *(const bf16x8*)&Vs[cur][vr + rc0];
            bf16x8 vf1 = *(const bf16x8*)&Vs[cur][vr + rc1];
            o[td] = __builtin_amdgcn_mfma_f32_16x16x32_bf16(pf0, vf0, o[td], 0, 0, 0);
            o[td] = __builtin_amdgcn_mfma_f32_16x16x32_bf16(pf1, vf1, o[td], 0, 0, 0);
        }
    }
    float lr4[4];
    #pragma unroll
    for (int r = 0; r < 4; r++) lr4[r] = __shfl(lrow, q4 + r);
    #pragma unroll
    for (int td = 0; td < 4; td++) {
        #pragma unroll
        for (int r = 0; r < 4; r++) {
            int row = q0 + wave * 16 + q4 + r;
            int col = h * 64 + td * 16 + ln16;
            ob[((size_t)(b * 1024 + row)) * 1024 + col] = f2bf(o[td][r] / lr4[r]);
        }
    }
}

// ------- batched weight transpose + bf16: in fp32 [z][K][N] -> out bf16 [z][N][K] ----
__global__ __launch_bounds__(256) void wtrans_kernel(const float* __restrict__ in,
                                                     unsigned short* __restrict__ out,
                                                     int K, int N) {
    __shared__ float t[64][65];
    int n0 = blockIdx.x * 64, k0 = blockIdx.y * 64, z = blockIdx.z;
    in  += (size_t)z * K * N;
    out += (size_t)z * N * K;
    for (int i = threadIdx.x; i < 4096; i += 256) {
        int kr = i >> 6, nc = i & 63;
        t[kr][nc] = in[(size_t)(k0 + kr) * N + n0 + nc];
    }
    __syncthreads();
    for (int i = threadIdx.x; i < 4096; i += 256) {
        int nr = i >> 6, kc = i & 63;
        out[(size_t)(n0 + nr) * K + k0 + kc] = f2bf(t[kc][nr]);
    }
}

// ------- bf16 MFMA GEMM, BK=64, XOR-swizzled LDS -------------------------------
// C = act(A@B + bias)[+C]; A[M][lda] bf16, Bt[N][lda] bf16.
// SPLITK: blockIdx.z selects K-chunk of size K; raw partials to Cf + z*M*N.
template <int BM, int BN, int WM, int WN, int ACT, bool ADDC, bool OUTBF16, bool SPLITK>
__global__ __launch_bounds__(256) void gemm_bf16(const unsigned short* __restrict__ A,
                                                 const unsigned short* __restrict__ Bt,
                                                 const float* __restrict__ bias,
                                                 float* __restrict__ Cf,
                                                 unsigned short* __restrict__ Cb,
                                                 int M, int N, int K, int lda) {
    constexpr int MT = BM / (WM * 16);
    constexpr int NT = BN / (WN * 16);
    __shared__ short As[BM * 64];
    __shared__ short Bs[BN * 64];
    int tid = threadIdx.x;
    int lane = tid & 63, wave = tid >> 6;
    int wm = wave / WN, wn = wave % WN;
    int ln16 = lane & 15, q = lane >> 4;
    int m0 = blockIdx.y * BM, n0 = blockIdx.x * BN;
    int kOff = SPLITK ? blockIdx.z * K : 0;

    floatx4 acc[MT][NT];
    #pragma unroll
    for (int i = 0; i < MT; i++)
        #pragma unroll
        for (int j = 0; j < NT; j++) acc[i][j] = (floatx4){0.f, 0.f, 0.f, 0.f};

    int kSteps = K >> 6;
    for (int ks = 0; ks < kSteps; ks++) {
        int k0 = kOff + (ks << 6);
        #pragma unroll
        for (int it = 0; it < BM / 32; it++) {
            int i = tid + it * 256;
            int row = i >> 3, gc = (i & 7) ^ (row & 7);   // XOR chunk swizzle
            load_lds16(A + (size_t)(m0 + row) * lda + k0 + gc * 8, &As[i * 8]);
        }
        #pragma unroll
        for (int it = 0; it < BN / 32; it++) {
            int i = tid + it * 256;
            int row = i >> 3, gc = (i & 7) ^ (row & 7);
            load_lds16(Bt + (size_t)(n0 + row) * lda + k0 + gc * 8, &Bs[i * 8]);
        }
        __syncthreads();
        bf16x8 af[2][MT], bf[2][NT];
        #pragma unroll
        for (int h = 0; h < 2; h++) {
            #pragma unroll
            for (int mi = 0; mi < MT; mi++) {
                int row = wm * (BM / WM) + mi * 16 + ln16;
                af[h][mi] = *(const bf16x8*)&As[row * 64 + (((h * 4 + q) ^ (row & 7)) * 8)];
            }
            #pragma unroll
            for (int ni = 0; ni < NT; ni++) {
                int row = wn * (BN / WN) + ni * 16 + ln16;
                bf[h][ni] = *(const bf16x8*)&Bs[row * 64 + (((h * 4 + q) ^ (row & 7)) * 8)];
            }
        }
        #pragma unroll
        for (int h = 0; h < 2; h++)
            #pragma unroll
            for (int mi = 0; mi < MT; mi++)
                #pragma unroll
                for (int ni = 0; ni < NT; ni++)
                    acc[mi][ni] = __builtin_amdgcn_mfma_f32_16x16x32_bf16(af[h][mi], bf[h][ni], acc[mi][ni], 0, 0, 0);
        __syncthreads();
    }

    int q4 = q * 4;
    float* Cp = SPLITK ? (Cf + (size_t)blockIdx.z * M * N) : Cf;
    #pragma unroll
    for (int ni = 0; ni < NT; ni++) {
        int col = n0 + wn * (BN / WN) + ni * 16 + ln16;
        float bv = SPLITK ? 0.f : bias[col];
        #pragma unroll
        for (int mi = 0; mi < MT; mi++) {
            #pragma unroll
            for (int r = 0; r < 4; r++) {
                int row = m0 + wm * (BM / WM) + mi * 16 + q4 + r;
                size_t off = (size_t)row * N + col;
                float v = acc[mi][ni][r] + bv;
                if (!SPLITK && ACT == 1) v = 0.5f * v * (1.f + erff(v * 0.70710678118654752f));
                if (!SPLITK && ADDC) v += Cf[off];
                if (!SPLITK && OUTBF16) Cb[off] = f2bf(v);
                else Cp[off] = v;
            }
        }
    }
}

// ------- fused split-K reduce + layernorm: x = xb + P0 + P1 + bias -> xb, LN(x) -> Y ----
__global__ __launch_bounds__(256) void skln_kernel(const float* __restrict__ P,
                                                   const float* __restrict__ bias,
                                                   float* __restrict__ xb,
                                                   unsigned short* __restrict__ Y,
                                                   const float* __restrict__ g,
                                                   const float* __restrict__ b,
                                                   float eps, int affine) {
    int row = blockIdx.x;                        // 2048 rows
    int t = threadIdx.x;
    int idx = row * 256 + t;                     // float4 index
    float4 a = ((const float4*)P)[idx];
    float4 c = ((const float4*)P)[idx + 524288];
    float4 x = ((float4*)xb)[idx];
    const float4 bb = *(const float4*)(bias + t * 4);
    x.x += a.x + c.x + bb.x;
    x.y += a.y + c.y + bb.y;
    x.z += a.z + c.z + bb.z;
    x.w += a.w + c.w + bb.w;
    ((float4*)xb)[idx] = x;
    float s = x.x + x.y + x.z + x.w;
    float sq = x.x * x.x + x.y * x.y + x.z * x.z + x.w * x.w;
    __shared__ float red[8];
    #pragma unroll
    for (int off = 32; off; off >>= 1) { s += __shfl_xor(s, off); sq += __shfl_xor(sq, off); }
    int wid = t >> 6, lane = t & 63;
    if (!lane) { red[wid] = s; red[wid + 4] = sq; }
    __syncthreads();
    s = red[0] + red[1] + red[2] + red[3];
    sq = red[4] + red[5] + red[6] + red[7];
    float mu = s * (1.f / 1024.f);
    float var = sq * (1.f / 1024.f) - mu * mu;
    float rs = rsqrtf(var + eps);
    int cidx = t * 4;
    float4 y;
    if (affine) {
        y.x = (x.x - mu) * rs * g[cidx + 0] + b[cidx + 0];
        y.y = (x.y - mu) * rs * g[cidx + 1] + b[cidx + 1];
        y.z = (x.z - mu) * rs * g[cidx + 2] + b[cidx + 2];
        y.w = (x.w - mu) * rs * g[cidx + 3] + b[cidx + 3];
    } else {
        y.x = (x.x - mu) * rs; y.y = (x.y - mu) * rs;
        y.z = (x.z - mu) * rs; y.w = (x.w - mu) * rs;
    }
    ushort4 o;
    o.x = f2bf(y.x); o.y = f2bf(y.y); o.z = f2bf(y.z); o.w = f2bf(y.w);
    *(ushort4*)(Y + (size_t)row * 1024 + cidx) = o;
}

// ---------------- unpatchify ----------------
__global__ void unpatchify_kernel(const float* __restrict__ xf, float* __restrict__ img) {
    int idx = blockIdx.x * 256 + threadIdx.x;
    int x = idx & 63, y = (idx >> 6) & 63, ch = (idx >> 12) & 63, b = idx >> 18;
    int hh = y >> 1, ww = x >> 1, p = y & 1, qq = x & 1;
    img[idx] = xf[((size_t)b * 1024 + hh * 32 + ww) * 256 + ch * 4 + p * 2 + qq];
}

// ------- conv1: 64->16, 3x3, pad1, relu -------
__global__ __launch_bounds__(256) void conv1_kernel(const float* __restrict__ img,
                                                    const float* __restrict__ w,
                                                    const float* __restrict__ bias,
                                                    float* __restrict__ out) {
    __shared__ float Ls[64 * 3 * 66];
    __shared__ float Ws[16 * 580];
    int tid = threadIdx.x;
    int y = blockIdx.x, b = blockIdx.y;
    for (int i = tid; i < 9216; i += 256) {
        int oc = i / 576, rem = i % 576;
        Ws[oc * 580 + rem] = w[i];
    }
    for (int i = tid; i < 12288; i += 256) {
        int r = i >> 6, x = i & 63;
        int ic = r / 3, ky = r % 3;
        int yy = y + ky - 1;
        float v = (yy >= 0 && yy < 64) ? img[((size_t)(b * 64 + ic) * 64 + yy) * 64 + x] : 0.f;
        Ls[(ic * 3 + ky) * 66 + x + 1] = v;
        if (x == 0)  Ls[(ic * 3 + ky) * 66 + 0]  = 0.f;
        if (x == 63) Ls[(ic * 3 + ky) * 66 + 65] = 0.f;
    }
    __syncthreads();
    int oc = tid >> 4, xg = (tid & 15) * 4;
    float bv = bias[oc];
    float acc0 = bv, acc1 = bv, acc2 = bv, acc3 = bv;
    for (int ic = 0; ic < 64; ic++) {
        const float* wr = &Ws[oc * 580 + ic * 9];
        float w00 = wr[0], w01 = wr[1], w02 = wr[2];
        float w10 = wr[3], w11 = wr[4], w12 = wr[5];
        float w20 = wr[6], w21 = wr[7], w22 = wr[8];
        const float* l0 = &Ls[(ic * 3 + 0) * 66 + xg];
        const float* l1 = &Ls[(ic * 3 + 1) * 66 + xg];
        const float* l2 = &Ls[(ic * 3 + 2) * 66 + xg];
        float a0 = l0[0], a1 = l0[1], a2 = l0[2], a3 = l0[3], a4 = l0[4], a5 = l0[5];
        float b0 = l1[0], b1 = l1[1], b2 = l1[2], b3 = l1[3], b4 = l1[4], b5 = l1[5];
        float c0 = l2[0], c1 = l2[1], c2 = l2[2], c3 = l2[3], c4 = l2[4], c5 = l2[5];
        acc0 += a0*w00 + a1*w01 + a2*w02 + b0*w10 + b1*w11 + b2*w12 + c0*w20 + c1*w21 + c2*w22;
        acc1 += a1*w00 + a2*w01 + a3*w02 + b1*w10 + b2*w11 + b3*w12 + c1*w20 + c2*w21 + c3*w22;
        acc2 += a2*w00 + a3*w01 + a4*w02 + b2*w10 + b3*w11 + b4*w12 + c2*w20 + c3*w21 + c4*w22;
        acc3 += a3*w00 + a4*w01 + a5*w02 + b3*w10 + b4*w11 + b5*w12 + c3*w20 + c4*w21 + c5*w22;
    }
    float* op = out + (((size_t)(b * 16 + oc) * 64 + y) * 64 + xg);
    op[0] = fmaxf(acc0, 0.f);
    op[1] = fmaxf(acc1, 0.f);
    op[2] = fmaxf(acc2, 0.f);
    op[3] = fmaxf(acc3, 0.f);
}

// ------- conv2: 16->3, 3x3, pad1 -------
__global__ __launch_bounds__(256) void conv2_kernel(const float* __restrict__ in,
                                                    const float* __restrict__ w,
                                                    const float* __restrict__ bias,
                                                    float* __restrict__ out) {
    __shared__ float Ls[16 * 3 * 66];
    __shared__ float Ws[3 * 160];
    int tid = threadIdx.x;
    int y = blockIdx.x, b = blockIdx.y;
    for (int i = tid; i < 432; i += 256) {
        int oc = i / 144, rem = i % 144;
        Ws[oc * 160 + rem] = w[i];
    }
    for (int i = tid; i < 3072; i += 256) {
        int r = i >> 6, x = i & 63;
        int ic = r / 3, ky = r % 3;
        int yy = y + ky - 1;
        float v = (yy >= 0 && yy < 64) ? in[((size_t)(b * 16 + ic) * 64 + yy) * 64 + x] : 0.f;
        Ls[(ic * 3 + ky) * 66 + x + 1] = v;
        if (x == 0)  Ls[(ic * 3 + ky) * 66 + 0]  = 0.f;
        if (x == 63) Ls[(ic * 3 + ky) * 66 + 65] = 0.f;
    }
    __syncthreads();
    int oc = tid >> 6, x = tid & 63;
    if (oc < 3) {
        float acc = bias[oc];
        for (int ic = 0; ic < 16; ic++) {
            const float* wr = &Ws[oc * 160 + ic * 9];
            const float* l0 = &Ls[(ic * 3 + 0) * 66 + x];
            const float* l1 = &Ls[(ic * 3 + 1) * 66 + x];
            const float* l2 = &Ls[(ic * 3 + 2) * 66 + x];
            acc += l0[0]*wr[0] + l0[1]*wr[1] + l0[2]*wr[2]
                 + l1[0]*wr[3] + l1[1]*wr[4] + l1[2]*wr[5]
                 + l2[0]*wr[6] + l2[1]*wr[7] + l2[2]*wr[8];
        }
        out[((size_t)(b * 3 + oc) * 64 + y) * 64 + x] = acc;
    }
}

// ---------------- launch ----------------
extern "C" void kernel_launch(void* const* d_in, const int* in_sizes, int n_in,
                              void* d_out, int out_size, void* d_ws, size_t ws_size,
                              hipStream_t stream) {
    const float* x_in   = (const float*)d_in[0];
    const float* qkv_w  = (const float*)d_in[1];
    const float* qkv_b  = (const float*)d_in[2];
    const float* proj_w = (const float*)d_in[3];
    const float* proj_b = (const float*)d_in[4];
    const float* nq_g   = (const float*)d_in[5];
    const float* nq_b   = (const float*)d_in[6];
    const float* nk_g   = (const float*)d_in[7];
    const float* nk_b   = (const float*)d_in[8];
    const float* n1_g   = (const float*)d_in[9];
    const float* n1_b   = (const float*)d_in[10];
    const float* n2_g   = (const float*)d_in[11];
    const float* n2_b   = (const float*)d_in[12];
    const float* fc1_w  = (const float*)d_in[13];
    const float* fc1_b  = (const float*)d_in[14];
    const float* fc2_w  = (const float*)d_in[15];
    const float* fc2_b  = (const float*)d_in[16];
    const float* fin_w  = (const float*)d_in[17];
    const float* fin_b  = (const float*)d_in[18];
    const float* c1_w   = (const float*)d_in[19];
    const float* c1_b   = (const float*)d_in[20];
    const float* c2_w   = (const float*)d_in[21];
    const float* c2_b   = (const float*)d_in[22];
    float* out = (float*)d_out;

    char* w = (char*)d_ws;
    float* xb           = (float*)w;          w += (size_t)2 * 1024 * 1024 * 4;
    unsigned short* hnb = (unsigned short*)w; w += (size_t)2 * 1024 * 1024 * 2;
    float* qkv          = (float*)w;          w += (size_t)2 * 1024 * 3072 * 4;
    unsigned short* obb = (unsigned short*)w; w += (size_t)2 * 1024 * 1024 * 2;
    unsigned short* mhb = (unsigned short*)w; w += (size_t)2 * 1024 * 4096 * 2;
    float* xf           = (float*)w;          w += (size_t)2 * 1024 * 256 * 4;
    float* img          = (float*)w;          w += (size_t)2 * 64 * 64 * 64 * 4;
    float* c1o          = (float*)w;          w += (size_t)2 * 16 * 64 * 64 * 4;
    unsigned short* Qb  = (unsigned short*)w; w += (size_t)2 * 1024 * 1024 * 2;
    unsigned short* Kb  = (unsigned short*)w; w += (size_t)2 * 1024 * 1024 * 2;
    unsigned short* Vt  = (unsigned short*)w; w += (size_t)2 * 16 * 64 * 1024 * 2;
    float* skb          = (float*)w;          w += (size_t)2 * 2048 * 1024 * 4;   // split-K partials
    unsigned short* WQ  = (unsigned short*)w; w += (size_t)4 * 1024 * 3072 * 2;
    unsigned short* WP  = (unsigned short*)w; w += (size_t)4 * 1024 * 1024 * 2;
    unsigned short* W1  = (unsigned short*)w; w += (size_t)4 * 1024 * 4096 * 2;
    unsigned short* W2  = (unsigned short*)w; w += (size_t)4 * 4096 * 1024 * 2;
    unsigned short* WF  = (unsigned short*)w; w += (size_t)1024 * 256 * 2;

    wtrans_kernel<<<dim3(48, 16, 4), 256, 0, stream>>>(qkv_w, WQ, 1024, 3072);
    wtrans_kernel<<<dim3(16, 16, 4), 256, 0, stream>>>(proj_w, WP, 1024, 1024);
    wtrans_kernel<<<dim3(64, 16, 4), 256, 0, stream>>>(fc1_w, W1, 1024, 4096);
    wtrans_kernel<<<dim3(16, 64, 4), 256, 0, stream>>>(fc2_w, W2, 4096, 1024);
    wtrans_kernel<<<dim3(4, 16, 1), 256, 0, stream>>>(fin_w, WF, 1024, 256);

    posembed_kernel<<<8192, 256, 0, stream>>>(x_in, xb);

    for (int i = 0; i < 4; i++) {
        if (i == 0)
            ln_kernel<<<2048, 256, 0, stream>>>(xb, hnb, n1_g, n1_b, 1e-5f, 1);
        gemm_bf16<64, 128, 2, 2, 0, false, false, false><<<dim3(24, 32), 256, 0, stream>>>(
            hnb, WQ + (size_t)i * 3072 * 1024, qkv_b + i * 3072, qkv, nullptr, 2048, 3072, 1024, 1024);
        qkvprep_kernel<<<dim3(16, 16, 2), 256, 0, stream>>>(
            qkv, nq_g + i * 64, nq_b + i * 64, nk_g + i * 64, nk_b + i * 64, Qb, Kb, Vt);
        attn_mfma<<<dim3(16, 16, 2), 256, 0, stream>>>(Qb, Kb, Vt, obb);
        gemm_bf16<64, 64, 2, 2, 0, true, false, false><<<dim3(16, 32), 256, 0, stream>>>(
            obb, WP + (size_t)i * 1024 * 1024, proj_b + i * 1024, xb, nullptr, 2048, 1024, 1024, 1024);
        ln_kernel<<<2048, 256, 0, stream>>>(xb, hnb, n2_g + i * 1024, n2_b + i * 1024, 1e-5f, 1);
        gemm_bf16<64, 128, 2, 2, 1, false, true, false><<<dim3(32, 32), 256, 0, stream>>>(
            hnb, W1 + (size_t)i * 4096 * 1024, fc1_b + i * 4096, nullptr, mhb, 2048, 4096, 1024, 1024);
        gemm_bf16<64, 64, 2, 2, 0, false, false, true><<<dim3(16, 32, 2), 256, 0, stream>>>(
            mhb, W2 + (size_t)i * 1024 * 4096, fc2_b + i * 1024, skb, nullptr, 2048, 1024, 2048, 4096);
        // fused: xb += P0+P1+bias; hnb = LN(xb) (next block's ln1, or the final eps=1e-6 LN)
        if (i < 3)
            skln_kernel<<<2048, 256, 0, stream>>>(skb, fc2_b + i * 1024, xb, hnb,
                                                  n1_g + (i + 1) * 1024, n1_b + (i + 1) * 1024, 1e-5f, 1);
        else
            skln_kernel<<<2048, 256, 0, stream>>>(skb, fc2_b + i * 1024, xb, hnb,
                                                  nullptr, nullptr, 1e-6f, 0);
    }

    gemm_bf16<64, 64, 2, 2, 0, false, false, false><<<dim3(4, 32), 256, 0, stream>>>(
        hnb, WF, fin_b, xf, nullptr, 2048, 256, 1024, 1024);
    unpatchify_kernel<<<2048, 256, 0, stream>>>(xf, img);
    conv1_kernel<<<dim3(64, 2), 256, 0, stream>>>(img, c1_w, c1_b, c1o);
    conv2_kernel<<<dim3(64, 2), 256, 0, stream>>>(c1o, c2_w, c2_b, out);
}